// Round 4
// baseline (1351.717 us; speedup 1.0000x reference)
//
#include <hip/hip_runtime.h>

#define H 128

typedef __bf16 bf8_t __attribute__((ext_vector_type(8)));
typedef float  f4_t  __attribute__((ext_vector_type(4)));

#define MFMA16(a, b, c) __builtin_amdgcn_mfma_f32_16x16x32_bf16((a), (b), (c), 0, 0, 0)

__device__ __forceinline__ float silu_f(float v) {
    return v * (1.0f / (1.0f + __expf(-v)));
}

__device__ __forceinline__ float wload(const void* p, int idx, bool f32) {
    return f32 ? ((const float*)p)[idx] : (float)((const __bf16*)p)[idx];
}

__device__ __forceinline__ bf8_t hload8(const void* p, size_t off, bool f32) {
    bf8_t v;
    if (f32) {
        const float4* q = (const float4*)((const float*)p + off);
        const float4 a = q[0], b = q[1];
        v[0]=(__bf16)a.x; v[1]=(__bf16)a.y; v[2]=(__bf16)a.z; v[3]=(__bf16)a.w;
        v[4]=(__bf16)b.x; v[5]=(__bf16)b.y; v[6]=(__bf16)b.z; v[7]=(__bf16)b.w;
    } else {
        v = *(const bf8_t*)((const __bf16*)p + off);
    }
    return v;
}

__device__ __forceinline__ int eidx(const void* ei, int i, bool i64) {
    return i64 ? (int)((const long long*)ei)[i] : ((const int*)ei)[i];
}

__device__ __forceinline__ unsigned int pkbf(float a, float b) {
    const __bf16 x = (__bf16)a, y = (__bf16)b;
    return ((unsigned int)__builtin_bit_cast(unsigned short, y) << 16) |
           (unsigned int)__builtin_bit_cast(unsigned short, x);
}

// ---------------------------------------------------------------------------
// dtype detection
// ---------------------------------------------------------------------------
__global__ void detect_kernel(const unsigned short* __restrict__ hraw,
                              const int* __restrict__ eiraw, int* __restrict__ flags)
{
    __shared__ int s_nf, s_oddnz;
    if (threadIdx.x == 0) { s_nf = 0; s_oddnz = 0; }
    __syncthreads();
    int nf = 0;
    for (int i = threadIdx.x; i < 16384; i += blockDim.x) {
        const unsigned short u = hraw[i];
        if (((u >> 7) & 0xFF) == 0xFF) nf++;
    }
    int onz = 0;
    for (int i = threadIdx.x; i < 512; i += blockDim.x) {
        if (eiraw[2*i + 1] != 0) onz++;
    }
    if (nf)  atomicAdd(&s_nf, nf);
    if (onz) atomicAdd(&s_oddnz, onz);
    __syncthreads();
    if (threadIdx.x == 0) {
        flags[0] = (s_nf > 0) ? 1 : 0;
        flags[1] = (s_oddnz == 0) ? 1 : 0;
    }
}

// ---------------------------------------------------------------------------
// CSR build: dst histogram (raw ei) -> scan -> scatter+geometry (fused)
// ---------------------------------------------------------------------------
__global__ void histd_kernel(const void* __restrict__ ei, int* __restrict__ cnt,
                             const int* __restrict__ flags, int Ee)
{
    const int e = blockIdx.x*blockDim.x + threadIdx.x;
    if (e < Ee) atomicAdd(&cnt[eidx(ei, Ee + e, flags[1] != 0)], 1);
}

__global__ void scanA_kernel(const int* __restrict__ cnt, int* __restrict__ bsum, int Nn)
{
    __shared__ int s[512];
    const int gi = blockIdx.x*512 + threadIdx.x;
    s[threadIdx.x] = (gi < Nn) ? cnt[gi] : 0;
    __syncthreads();
    for (int off = 256; off > 0; off >>= 1) {
        if (threadIdx.x < off) s[threadIdx.x] += s[threadIdx.x + off];
        __syncthreads();
    }
    if (threadIdx.x == 0) bsum[blockIdx.x] = s[0];
}

__global__ void scanB_kernel(int* __restrict__ bsum, int* __restrict__ base, int nCh)
{
    if (threadIdx.x == 0) {
        int acc = 0;
        for (int b = 0; b < nCh; ++b) { base[b] = acc; acc += bsum[b]; }
    }
}

__global__ void scanC_kernel(const int* __restrict__ cnt, const int* __restrict__ base,
                             int* __restrict__ off, int* __restrict__ cursor, int Nn)
{
    __shared__ int s[512];
    const int i  = threadIdx.x;
    const int gi = blockIdx.x*512 + i;
    const int v  = (gi < Nn) ? cnt[gi] : 0;
    s[i] = v;
    __syncthreads();
    for (int o = 1; o < 512; o <<= 1) {
        const int t = (i >= o) ? s[i - o] : 0;
        __syncthreads();
        s[i] += t;
        __syncthreads();
    }
    const int excl = s[i] - v;
    if (gi <= Nn) {
        const int val = base[blockIdx.x] + excl;
        off[gi] = val;
        if (gi < Nn) cursor[gi] = val;
    }
}

// scatter + geometry: compute sorted slot, write srcs/dsts/rel4 at slot
__global__ void scatgeo_kernel(const void* __restrict__ ei, int* __restrict__ cursor,
                               int* __restrict__ srcs, int* __restrict__ dsts,
                               float4* __restrict__ rel4, const void* __restrict__ x,
                               const int* __restrict__ flags, int Ee)
{
    const int e = blockIdx.x*blockDim.x + threadIdx.x;
    if (e >= Ee) return;
    const bool i64 = flags[1] != 0;
    const bool f32 = flags[0] != 0;
    const int s = eidx(ei, e, i64);
    const int d = eidx(ei, Ee + e, i64);
    const int p = atomicAdd(&cursor[d], 1);
    srcs[p] = s;
    dsts[p] = d;
    float r[3];
    #pragma unroll
    for (int c = 0; c < 3; ++c)
        r[c] = wload(x, s*3 + c, f32) - wload(x, d*3 + c, f32);
    float4 o; o.x = r[0]; o.y = r[1]; o.z = r[2];
    o.w = r[0]*r[0] + r[1]*r[1] + r[2]*r[2];
    rel4[p] = o;
}

// ---------------------------------------------------------------------------
// Projection kernel: PB[n][0:128]   = (h @ We1[0:128])[n]
//                    PB[n][128:256] = (h @ We1[128:256])[n] + be1
// ---------------------------------------------------------------------------
__global__ __launch_bounds__(512, 2)
void proj_kernel(const void* __restrict__ h, const void* __restrict__ We1,
                 const void* __restrict__ be1, const int* __restrict__ flags,
                 __bf16* __restrict__ PB, int Nn)
{
    const bool f32 = flags[0] != 0;
    const int tid  = threadIdx.x;
    const int wv   = tid >> 6;
    const int lane = tid & 63;
    const int quad = lane >> 4;
    const int l15  = lane & 15;

    bf8_t bW[4][2];
    float bias[2];
    #pragma unroll
    for (int t = 0; t < 2; ++t) {
        const int n    = wv*32 + t*16 + l15;
        const int rb   = (n < 128) ? 0 : 128;
        const int col  = n & 127;
        #pragma unroll
        for (int kc = 0; kc < 4; ++kc) {
            bf8_t v;
            #pragma unroll
            for (int j = 0; j < 8; ++j)
                v[j] = (__bf16)wload(We1, (rb + kc*32 + quad*8 + j)*H + col, f32);
            bW[kc][t] = v;
        }
        bias[t] = (n < 128) ? 0.f : wload(be1, col, f32);
    }

    __shared__ __bf16 s_h[32*136];

    const int tiles = (Nn + 31) >> 5;
    for (int tile = blockIdx.x; tile < tiles; tile += gridDim.x) {
        const int nb = tile << 5;
        __syncthreads();
        {
            const int m = tid >> 4, c = tid & 15;
            int node = nb + m; if (node >= Nn) node = Nn - 1;
            *(bf8_t*)&s_h[m*136 + c*8] = hload8(h, (size_t)node*H + c*8, f32);
        }
        __syncthreads();

        f4_t acc[2][2];
        #pragma unroll
        for (int mm = 0; mm < 2; ++mm)
            #pragma unroll
            for (int t = 0; t < 2; ++t) acc[mm][t] = (f4_t){0.f,0.f,0.f,0.f};
        #pragma unroll
        for (int kc = 0; kc < 4; ++kc) {
            #pragma unroll
            for (int mm = 0; mm < 2; ++mm) {
                const bf8_t a = *(const bf8_t*)&s_h[(mm*16 + l15)*136 + quad*8 + kc*32];
                acc[mm][0] = MFMA16(a, bW[kc][0], acc[mm][0]);
                acc[mm][1] = MFMA16(a, bW[kc][1], acc[mm][1]);
            }
        }
        #pragma unroll
        for (int mm = 0; mm < 2; ++mm)
            #pragma unroll
            for (int i = 0; i < 4; ++i) {
                const int row = nb + mm*16 + quad*4 + i;
                if (row < Nn) {
                    #pragma unroll
                    for (int t = 0; t < 2; ++t)
                        PB[(size_t)row*256 + wv*32 + t*16 + l15] =
                            (__bf16)(acc[mm][t][i] + bias[t]);
                }
            }
    }
}

// ---------------------------------------------------------------------------
// R9 edge kernel: barrier-free per-wave pipeline via swapped-operand MFMA.
// A = prepacked weight fragments (block-shared LDS), B = per-wave activation
// fragments -> output has edge in lane&15, feature in quad position.
// Each wave independently processes 16-edge dst-sorted micro-tiles:
//   gather PB -> stage (silu) -> L2 32xMFMA -> bounce m2 via wave-private LDS
//   -> L3 32xMFMA -> coord head reduce (2 shfl_xor) -> in-wave msg segmented
//   reduce (interior runs: exactly-once stores; boundary runs: f32 atomics)
//   -> in-wave coord segmented scan.
// One __syncthreads total (after weight staging). 16 waves/block, 1 block/CU.
// ---------------------------------------------------------------------------
__global__ __launch_bounds__(1024)
void egnn_edge_wave_kernel(const __bf16* __restrict__ PB,
                           const int* __restrict__ srcs, const int* __restrict__ dsts,
                           const float4* __restrict__ rel4,
                           const void* __restrict__ We1,  // row 256 only (w1d)
                           const void* __restrict__ We2, const void* __restrict__ be2,
                           const void* __restrict__ Wc1, const void* __restrict__ bc1,
                           const void* __restrict__ Wc2, const int* __restrict__ flags,
                           float* __restrict__ msg, float* __restrict__ coord,
                           int Ee)
{
    const bool f32 = flags[0] != 0;
    const int tid  = threadIdx.x;
    const int wv   = tid >> 6;          // 0..15
    const int lane = tid & 63;
    const int quad = lane >> 4;
    const int l15  = lane & 15;

    // ---- block-shared prepacked weights + biases ----
    __shared__ __align__(16) __bf16 s_w2[2048*8];     // We2 A-frags, 32 KB
    __shared__ __align__(16) __bf16 s_wc[2048*8];     // Wc1 A-frags, 32 KB
    __shared__ __align__(16) float  s_bias[4][128];   // 0=w1d 1=be2 2=bc1 3=wc2
    // per-wave m2 bounce buffer: [edge 0..15][col 0..127], row stride 152 bf16
    __shared__ __align__(16) __bf16 s_m2w[16][16*152];

    for (int f = tid; f < 2048; f += 1024) {
        const int g = f >> 8, kc = (f >> 6) & 3, ln = f & 63;
        const int qd = ln >> 4, l = ln & 15;
        bf8_t v, u;
        #pragma unroll
        for (int j = 0; j < 8; ++j) {
            const int k = kc*32 + qd*8 + j;
            v[j] = (__bf16)wload(We2, k*H + g*16 + l, f32);
            u[j] = (__bf16)wload(Wc1, k*H + g*16 + l, f32);
        }
        *(bf8_t*)&s_w2[f*8] = v;
        *(bf8_t*)&s_wc[f*8] = u;
    }
    if (tid < 512) {
        const int a = tid >> 7, c = tid & 127;
        float v;
        if      (a == 0) v = wload(We1, 256*H + c, f32);
        else if (a == 1) v = wload(be2, c, f32);
        else if (a == 2) v = wload(bc1, c, f32);
        else             v = wload(Wc2, c, f32);
        s_bias[a][c] = v;
    }
    __syncthreads();

    const int tiles  = (Ee + 15) >> 4;
    const int stride = gridDim.x * 16;
    const float* rw  = (const float*)rel4;
    int mt = blockIdx.x*16 + wv;
    if (mt >= tiles) return;

    // ---- prologue: indices + PB gather for first micro-tile ----
    int e0 = mt*16 + l15; if (e0 >= Ee) e0 = Ee - 1;
    float d2c = rw[(size_t)e0*4 + 3];
    int dval;
    bf8_t rS[4], rD[4];
    {
        const int sc = srcs[e0], dc = dsts[e0];
        dval = (mt*16 + l15 < Ee) ? dc : -1;
        #pragma unroll
        for (int kc = 0; kc < 4; ++kc) {
            rS[kc] = *(const bf8_t*)(PB + (size_t)sc*256 + kc*32 + quad*8);
            rD[kc] = *(const bf8_t*)(PB + (size_t)dc*256 + 128 + kc*32 + quad*8);
        }
    }

    for (; mt < tiles; mt += stride) {
        // ---- next-tile indices (issue early; clamped, always safe) ----
        const int mtn = mt + stride;
        int e1 = mtn*16 + l15; if (e1 >= Ee) e1 = Ee - 1;
        const int sn = srcs[e1], dn = dsts[e1];
        const float d2n = rw[(size_t)e1*4 + 3];
        const int dvn = (mtn*16 + l15 < Ee) ? dn : -1;

        // ---- stage: m1 B-fragments (edge=l15, k=kc*32+quad*8+j) ----
        bf8_t m1f[4];
        #pragma unroll
        for (int kc = 0; kc < 4; ++kc) {
            const f4_t w0 = *(const f4_t*)&s_bias[0][kc*32 + quad*8];
            const f4_t w1 = *(const f4_t*)&s_bias[0][kc*32 + quad*8 + 4];
            bf8_t m;
            #pragma unroll
            for (int j = 0; j < 4; ++j) {
                const float f = (float)rS[kc][j] + (float)rD[kc][j] + d2c*w0[j];
                m[j] = (__bf16)silu_f(f);
            }
            #pragma unroll
            for (int j = 4; j < 8; ++j) {
                const float f = (float)rS[kc][j] + (float)rD[kc][j] + d2c*w1[j-4];
                m[j] = (__bf16)silu_f(f);
            }
            m1f[kc] = m;
        }

        // ---- L2: m2^T = We2^T(A) x m1^T(B), acc init = be2 ----
        {
            f4_t acc[8];
            #pragma unroll
            for (int g = 0; g < 8; ++g)
                acc[g] = *(const f4_t*)&s_bias[1][g*16 + quad*4];
            #pragma unroll
            for (int kc = 0; kc < 4; ++kc) {
                #pragma unroll
                for (int g = 0; g < 8; ++g) {
                    const bf8_t wf = *(const bf8_t*)&s_w2[((g*4 + kc)*64 + lane)*8];
                    acc[g] = MFMA16(wf, m1f[kc], acc[g]);
                }
            }
            // epi2: silu -> write m2 row (edge=l15) to wave-private LDS
            #pragma unroll
            for (int g = 0; g < 8; ++g) {
                const float v0 = silu_f(acc[g][0]);
                const float v1 = silu_f(acc[g][1]);
                const float v2 = silu_f(acc[g][2]);
                const float v3 = silu_f(acc[g][3]);
                uint2 w; w.x = pkbf(v0, v1); w.y = pkbf(v2, v3);
                *(uint2*)&s_m2w[wv][l15*152 + g*16 + quad*4] = w;
            }
        }

        // ---- prefetch next tile's PB gather (rS/rD dead now) ----
        #pragma unroll
        for (int kc = 0; kc < 4; ++kc) {
            rS[kc] = *(const bf8_t*)(PB + (size_t)sn*256 + kc*32 + quad*8);
            rD[kc] = *(const bf8_t*)(PB + (size_t)dn*256 + 128 + kc*32 + quad*8);
        }

        // ---- L3: coord head = Wc1^T(A) x m2^T(B from LDS), acc init = bc1 ----
        float cw;
        {
            f4_t a3[8];
            #pragma unroll
            for (int g = 0; g < 8; ++g)
                a3[g] = *(const f4_t*)&s_bias[2][g*16 + quad*4];
            #pragma unroll
            for (int kc = 0; kc < 4; ++kc) {
                const bf8_t bm = *(const bf8_t*)&s_m2w[wv][l15*152 + kc*32 + quad*8];
                #pragma unroll
                for (int g = 0; g < 8; ++g) {
                    const bf8_t wf = *(const bf8_t*)&s_wc[((g*4 + kc)*64 + lane)*8];
                    a3[g] = MFMA16(wf, bm, a3[g]);
                }
            }
            float p = 0.f;
            #pragma unroll
            for (int g = 0; g < 8; ++g) {
                const f4_t wc = *(const f4_t*)&s_bias[3][g*16 + quad*4];
                #pragma unroll
                for (int i = 0; i < 4; ++i)
                    p += silu_f(a3[g][i]) * wc[i];
            }
            p += __shfl_xor(p, 16, 64);
            p += __shfl_xor(p, 32, 64);
            cw = p;   // every lane: full coord weight for edge l15
        }

        // ---- msg segmented reduce over this wave's 16 sorted edges ----
        {
            const int c0 = lane << 1;
            const unsigned int* mw = (const unsigned int*)&s_m2w[wv][0];
            int curd, first = 1;
            float ax, ay;
            {
                curd = __builtin_amdgcn_readfirstlane(__shfl(dval, 0, 64));
                const unsigned int w = mw[lane];
                ax = __uint_as_float(w << 16);
                ay = __uint_as_float(w & 0xffff0000u);
            }
            #pragma unroll
            for (int i = 1; i < 16; ++i) {
                const int di = __builtin_amdgcn_readfirstlane(__shfl(dval, i, 64));
                const unsigned int w = mw[i*76 + lane];
                const float vx = __uint_as_float(w << 16);
                const float vy = __uint_as_float(w & 0xffff0000u);
                if (di != curd) {
                    if (curd >= 0) {
                        if (first) {
                            atomicAdd(&msg[(size_t)curd*H + c0],     ax);
                            atomicAdd(&msg[(size_t)curd*H + c0 + 1], ay);
                        } else {
                            float2 st; st.x = ax; st.y = ay;
                            *(float2*)&msg[(size_t)curd*H + c0] = st;   // interior run
                        }
                    }
                    first = 0;
                    curd = di; ax = vx; ay = vy;
                } else { ax += vx; ay += vy; }
            }
            if (curd >= 0) {   // trailing run: boundary -> atomic
                atomicAdd(&msg[(size_t)curd*H + c0],     ax);
                atomicAdd(&msg[(size_t)curd*H + c0 + 1], ay);
            }
        }

        // ---- coord segmented scan (lanes 0..15) ----
        if (lane < 16) {
            int e = mt*16 + lane; if (e >= Ee) e = Ee - 1;
            const int d = dval;
            const float4 r = rel4[e];
            float vx = r.x*cw, vy = r.y*cw, vz = r.z*cw;
            int cn = 1;
            #pragma unroll
            for (int k = 1; k < 16; k <<= 1) {
                const int   dk = __shfl_up(d,  k, 64);
                const float xk = __shfl_up(vx, k, 64);
                const float yk = __shfl_up(vy, k, 64);
                const float zk = __shfl_up(vz, k, 64);
                const int   ck = __shfl_up(cn, k, 64);
                if (lane >= k && dk == d) { vx += xk; vy += yk; vz += zk; cn += ck; }
            }
            const int dnx = __shfl_down(d, 1, 64);
            const bool runend = (lane == 15) || (dnx != d);
            if (runend && d >= 0) {
                const int rs = lane - cn + 1;
                if (rs == 0 || lane == 15) {
                    atomicAdd(&coord[(size_t)d*3 + 0], vx);
                    atomicAdd(&coord[(size_t)d*3 + 1], vy);
                    atomicAdd(&coord[(size_t)d*3 + 2], vz);
                } else {
                    coord[(size_t)d*3 + 0] = vx;
                    coord[(size_t)d*3 + 1] = vy;
                    coord[(size_t)d*3 + 2] = vz;
                }
            }
        }

        d2c = d2n; dval = dvn;
    }
}

// ---------------------------------------------------------------------------
// Node kernel: h_out = h + silu([h | msg] @ Wn1 + bn1) @ Wn2 + bn2
// msg is f32. Optionally also emits x_out = x + coord (do_x).
// ---------------------------------------------------------------------------
__global__ __launch_bounds__(512, 2)
void egnn_node_kernel(const void* __restrict__ h, const float* __restrict__ msg,
                      const void* __restrict__ Wn1, const void* __restrict__ bn1,
                      const void* __restrict__ Wn2, const void* __restrict__ bn2,
                      const int* __restrict__ flags, void* __restrict__ h_out,
                      const void* __restrict__ x, const float* __restrict__ coord,
                      size_t obase, int do_x, int Nn)
{
    const bool f32 = flags[0] != 0;
    const int tid  = threadIdx.x;
    const int wv   = tid >> 6;
    const int lane = tid & 63;
    const int quad = lane >> 4;
    const int l15  = lane & 15;
    const int mg   = wv >> 2;
    const int ng   = wv & 3;

    bf8_t bW1[8][2];
    bf8_t bW2[4][2];
    float b1v[2], b2v[2];
    #pragma unroll
    for (int t = 0; t < 2; ++t) {
        const int n = ng*32 + t*16 + l15;
        #pragma unroll
        for (int kc = 0; kc < 8; ++kc) {
            bf8_t v;
            #pragma unroll
            for (int j = 0; j < 8; ++j) v[j] = (__bf16)wload(Wn1, (kc*32 + quad*8 + j)*H + n, f32);
            bW1[kc][t] = v;
        }
        #pragma unroll
        for (int kc = 0; kc < 4; ++kc) {
            bf8_t v;
            #pragma unroll
            for (int j = 0; j < 8; ++j) v[j] = (__bf16)wload(Wn2, (kc*32 + quad*8 + j)*H + n, f32);
            bW2[kc][t] = v;
        }
        b1v[t] = wload(bn1, n, f32);
        b2v[t] = wload(bn2, n, f32);
    }

    __shared__ __bf16 s_in[32*264];
    __shared__ __bf16 s_t1[32*136];

    const int tiles = (Nn + 31) >> 5;
    for (int tile = blockIdx.x; tile < tiles; tile += gridDim.x) {
        const int nb = tile << 5;
        __syncthreads();
        #pragma unroll
        for (int r = 0; r < 2; ++r) {
            const int idx = tid + r*512;
            const int m = idx >> 5, c = idx & 31;
            int node = nb + m;
            if (node >= Nn) node = Nn - 1;
            if (c < 16) {
                *(bf8_t*)&s_in[m*264 + c*8] = hload8(h, (size_t)node*H + c*8, f32);
            } else {
                const float4* mp = (const float4*)(msg + (size_t)node*H + (c - 16)*8);
                const float4 v0 = mp[0], v1 = mp[1];
                __bf16* d = &s_in[m*264 + c*8];
                d[0] = (__bf16)v0.x; d[1] = (__bf16)v0.y; d[2] = (__bf16)v0.z; d[3] = (__bf16)v0.w;
                d[4] = (__bf16)v1.x; d[5] = (__bf16)v1.y; d[6] = (__bf16)v1.z; d[7] = (__bf16)v1.w;
            }
        }
        // x_out epilogue (independent of LDS)
        if (do_x && tid < 96) {
            const int m = tid / 3, c = tid - m*3;
            const int node = nb + m;
            if (node < Nn) {
                const float xv = wload(x, node*3 + c, f32);
                const float o = xv + coord[(size_t)node*3 + c];
                if (f32) ((float*)h_out)[obase + (size_t)node*3 + c] = o;
                else     ((__bf16*)h_out)[obase + (size_t)node*3 + c] = (__bf16)o;
            }
        }
        __syncthreads();

        {
            f4_t a0 = {0.f,0.f,0.f,0.f}, a1 = {0.f,0.f,0.f,0.f};
            const int abase = (mg*16 + l15)*264 + quad*8;
            #pragma unroll
            for (int kc = 0; kc < 8; ++kc) {
                const bf8_t a = *(const bf8_t*)&s_in[abase + kc*32];
                a0 = MFMA16(a, bW1[kc][0], a0);
                a1 = MFMA16(a, bW1[kc][1], a1);
            }
            #pragma unroll
            for (int i = 0; i < 4; ++i) {
                const int m = mg*16 + quad*4 + i;
                s_t1[m*136 + ng*32 + l15]      = (__bf16)silu_f(a0[i] + b1v[0]);
                s_t1[m*136 + ng*32 + 16 + l15] = (__bf16)silu_f(a1[i] + b1v[1]);
            }
        }
        __syncthreads();

        {
            f4_t a0 = {0.f,0.f,0.f,0.f}, a1 = {0.f,0.f,0.f,0.f};
            const int abase = (mg*16 + l15)*136 + quad*8;
            #pragma unroll
            for (int kc = 0; kc < 4; ++kc) {
                const bf8_t a = *(const bf8_t*)&s_t1[abase + kc*32];
                a0 = MFMA16(a, bW2[kc][0], a0);
                a1 = MFMA16(a, bW2[kc][1], a1);
            }
            #pragma unroll
            for (int i = 0; i < 4; ++i) {
                const int node = nb + mg*16 + quad*4 + i;
                if (node < Nn) {
                    const int n0 = ng*32 + l15, n1 = n0 + 16;
                    const size_t i0 = (size_t)node*H + n0, i1 = (size_t)node*H + n1;
                    const float h0 = f32 ? ((const float*)h)[i0] : (float)((const __bf16*)h)[i0];
                    const float h1 = f32 ? ((const float*)h)[i1] : (float)((const __bf16*)h)[i1];
                    const float o0 = a0[i] + b2v[0] + h0;
                    const float o1 = a1[i] + b2v[1] + h1;
                    if (f32) {
                        ((float*)h_out)[i0] = o0;
                        ((float*)h_out)[i1] = o1;
                    } else {
                        ((__bf16*)h_out)[i0] = (__bf16)o0;
                        ((__bf16*)h_out)[i1] = (__bf16)o1;
                    }
                }
            }
        }
    }
}

// ---------------------------------------------------------------------------
// Fallback (R2 atomic path)
// ---------------------------------------------------------------------------
__global__ void cvt_ei_kernel(const void* __restrict__ src, int* __restrict__ dst,
                              int n, const int* __restrict__ flags)
{
    const int i = blockIdx.x*blockDim.x + threadIdx.x;
    if (i >= n) return;
    dst[i] = flags[1] ? (int)((const long long*)src)[i] : ((const int*)src)[i];
}

__global__ __launch_bounds__(512, 2)
void egnn_edge_kernel(const void* __restrict__ h, const void* __restrict__ x,
                      const int* __restrict__ ei,
                      const void* __restrict__ We1, const void* __restrict__ be1,
                      const void* __restrict__ We2, const void* __restrict__ be2,
                      const void* __restrict__ Wc1, const void* __restrict__ bc1,
                      const void* __restrict__ Wc2, const int* __restrict__ flags,
                      float* __restrict__ msg_agg, float* __restrict__ coord_agg,
                      int Nn, int Ee)
{
    const bool f32 = flags[0] != 0;
    const int tid  = threadIdx.x;
    const int wv   = tid >> 6;
    const int lane = tid & 63;
    const int quad = lane >> 4;
    const int l15  = lane & 15;
    const int mg   = wv >> 2;
    const int ng   = wv & 3;

    bf8_t bW1[8][2];
    bf8_t bW2[4][2];
    bf8_t bWc[4][2];
    float be1v[2], be2v[2], bc1v[2], w1dv[2], wc2v[2];
    #pragma unroll
    for (int t = 0; t < 2; ++t) {
        const int n = ng*32 + t*16 + l15;
        #pragma unroll
        for (int kc = 0; kc < 8; ++kc) {
            bf8_t v;
            #pragma unroll
            for (int j = 0; j < 8; ++j) v[j] = (__bf16)wload(We1, (kc*32 + quad*8 + j)*H + n, f32);
            bW1[kc][t] = v;
        }
        #pragma unroll
        for (int kc = 0; kc < 4; ++kc) {
            bf8_t v, u;
            #pragma unroll
            for (int j = 0; j < 8; ++j) {
                v[j] = (__bf16)wload(We2, (kc*32 + quad*8 + j)*H + n, f32);
                u[j] = (__bf16)wload(Wc1, (kc*32 + quad*8 + j)*H + n, f32);
            }
            bW2[kc][t] = v;
            bWc[kc][t] = u;
        }
        be1v[t] = wload(be1, n, f32);
        be2v[t] = wload(be2, n, f32);
        bc1v[t] = wload(bc1, n, f32);
        w1dv[t] = wload(We1, 256*H + n, f32);
        wc2v[t] = wload(Wc2, n, f32);
    }

    __shared__ __bf16 s_in[32*264];
    __shared__ __bf16 s_m1[32*136];
    __shared__ __bf16 s_m2[32*136];
    __shared__ float  s_rel[32*3];
    __shared__ float  s_dist[32];
    __shared__ int    s_dstv[32];
    __shared__ float  s_cw[32*4];

    const int tiles = Ee >> 5;
    for (int tile = blockIdx.x; tile < tiles; tile += gridDim.x) {
        const int ebase = tile << 5;
        __syncthreads();

        if (tid < 32) {
            const int e  = ebase + tid;
            const int sn = ei[e];
            const int dn = ei[Ee + e];
            s_dstv[tid] = dn;
            float d2 = 0.f;
            #pragma unroll
            for (int c = 0; c < 3; ++c) {
                float r;
                if (f32) r = ((const float*)x)[sn*3 + c] - ((const float*)x)[dn*3 + c];
                else     r = (float)((const __bf16*)x)[sn*3 + c] - (float)((const __bf16*)x)[dn*3 + c];
                s_rel[tid*3 + c] = r;
                d2 += r*r;
            }
            s_dist[tid] = d2;
        }
        #pragma unroll
        for (int r = 0; r < 2; ++r) {
            const int idx = tid + r*512;
            const int m = idx >> 5, c = idx & 31;
            const int e = ebase + m;
            const int node = (c < 16) ? ei[e] : ei[Ee + e];
            *(bf8_t*)&s_in[m*264 + c*8] = hload8(h, (size_t)node*H + (c & 15)*8, f32);
        }
        __syncthreads();

        {
            f4_t a0 = {0.f,0.f,0.f,0.f}, a1 = {0.f,0.f,0.f,0.f};
            const int abase = (mg*16 + l15)*264 + quad*8;
            #pragma unroll
            for (int kc = 0; kc < 8; ++kc) {
                const bf8_t a = *(const bf8_t*)&s_in[abase + kc*32];
                a0 = MFMA16(a, bW1[kc][0], a0);
                a1 = MFMA16(a, bW1[kc][1], a1);
            }
            #pragma unroll
            for (int i = 0; i < 4; ++i) {
                const int m = mg*16 + quad*4 + i;
                const float d2 = s_dist[m];
                s_m1[m*136 + ng*32 + l15]      = (__bf16)silu_f(a0[i] + d2*w1dv[0] + be1v[0]);
                s_m1[m*136 + ng*32 + 16 + l15] = (__bf16)silu_f(a1[i] + d2*w1dv[1] + be1v[1]);
            }
        }
        __syncthreads();

        {
            f4_t a0 = {0.f,0.f,0.f,0.f}, a1 = {0.f,0.f,0.f,0.f};
            const int abase = (mg*16 + l15)*136 + quad*8;
            #pragma unroll
            for (int kc = 0; kc < 4; ++kc) {
                const bf8_t a = *(const bf8_t*)&s_m1[abase + kc*32];
                a0 = MFMA16(a, bW2[kc][0], a0);
                a1 = MFMA16(a, bW2[kc][1], a1);
            }
            #pragma unroll
            for (int i = 0; i < 4; ++i) {
                const int m = mg*16 + quad*4 + i;
                const float v0 = silu_f(a0[i] + be2v[0]);
                const float v1 = silu_f(a1[i] + be2v[1]);
                s_m2[m*136 + ng*32 + l15]      = (__bf16)v0;
                s_m2[m*136 + ng*32 + 16 + l15] = (__bf16)v1;
                const size_t db = (size_t)s_dstv[m]*H + ng*32 + l15;
                atomicAdd(&msg_agg[db],      v0);
                atomicAdd(&msg_agg[db + 16], v1);
            }
        }
        __syncthreads();

        {
            f4_t a0 = {0.f,0.f,0.f,0.f}, a1 = {0.f,0.f,0.f,0.f};
            const int abase = (mg*16 + l15)*136 + quad*8;
            #pragma unroll
            for (int kc = 0; kc < 4; ++kc) {
                const bf8_t a = *(const bf8_t*)&s_m2[abase + kc*32];
                a0 = MFMA16(a, bWc[kc][0], a0);
                a1 = MFMA16(a, bWc[kc][1], a1);
            }
            float p[4];
            #pragma unroll
            for (int i = 0; i < 4; ++i) {
                const float v0 = silu_f(a0[i] + bc1v[0]);
                const float v1 = silu_f(a1[i] + bc1v[1]);
                p[i] = v0*wc2v[0] + v1*wc2v[1];
            }
            #pragma unroll
            for (int off = 1; off < 16; off <<= 1) {
                #pragma unroll
                for (int i = 0; i < 4; ++i) p[i] += __shfl_xor(p[i], off, 64);
            }
            if (l15 == 0) {
                #pragma unroll
                for (int i = 0; i < 4; ++i)
                    s_cw[(mg*16 + quad*4 + i)*4 + ng] = p[i];
            }
        }
        __syncthreads();

        if (tid < 96) {
            const int m = tid / 3, c = tid - m*3;
            const float cw = s_cw[m*4 + 0] + s_cw[m*4 + 1] + s_cw[m*4 + 2] + s_cw[m*4 + 3];
            atomicAdd(&coord_agg[(size_t)s_dstv[m]*3 + c], s_rel[m*3 + c]*cw);
        }
    }
}

__global__ void egnn_x_kernel(const void* __restrict__ x, const float* __restrict__ coord_agg,
                              const int* __restrict__ flags, void* __restrict__ out,
                              size_t obase, int total)
{
    const bool f32 = flags[0] != 0;
    const int i = blockIdx.x*blockDim.x + threadIdx.x;
    if (i >= total) return;
    const float xv = f32 ? ((const float*)x)[i] : (float)((const __bf16*)x)[i];
    const float o = xv + coord_agg[i];
    if (f32) ((float*)out)[obase + i] = o;
    else     ((__bf16*)out)[obase + i] = (__bf16)o;
}

static inline size_t align256(size_t v) { return (v + 255) & ~(size_t)255; }

extern "C" void kernel_launch(void* const* d_in, const int* in_sizes, int n_in,
                              void* d_out, int out_size, void* d_ws, size_t ws_size,
                              hipStream_t stream)
{
    const void* h   = d_in[0];
    const void* x   = d_in[1];
    const void* ei0 = d_in[2];
    const void* We1 = d_in[3];
    const void* be1 = d_in[4];
    const void* We2 = d_in[5];
    const void* be2 = d_in[6];
    const void* Wc1 = d_in[7];
    const void* bc1 = d_in[8];
    const void* Wc2 = d_in[9];
    const void* Wn1 = d_in[10];
    const void* bn1 = d_in[11];
    const void* Wn2 = d_in[12];
    const void* bn2 = d_in[13];

    const int Nn = in_sizes[0] / H;   // 50000
    const int Ee = in_sizes[2] / 2;   // 640000

    char* ws = (char*)d_ws;
    size_t o = 0;
    // zero-init region: cnt | msg | coord (one memset)
    size_t o_cnt   = o; o = align256(o + (size_t)Nn*4);
    size_t o_msg   = o; o = align256(o + (size_t)Nn*H*4);      // msg_agg f32
    size_t o_coord = o; o = align256(o + (size_t)Nn*3*4);      // coord_agg f32
    const size_t zero_end = o;
    size_t o_srcs  = o; o = align256(o + (size_t)Ee*4);
    size_t o_dsts  = o; o = align256(o + (size_t)Ee*4);
    size_t o_rel   = o; o = align256(o + (size_t)Ee*16);       // rel4 (xyz, d2)
    size_t o_pb    = o; o = align256(o + (size_t)Nn*256*2);    // PB bf16 [N,256]
    size_t o_off   = o; o = align256(o + (size_t)(Nn+1)*4);
    size_t o_cur   = o; o = align256(o + (size_t)Nn*4);
    size_t o_bsum  = o; o = align256(o + 512*4);
    size_t o_base  = o; o = align256(o + 512*4);
    size_t o_flags = o; o = align256(o + 64);
    const size_t need_csr = o;

    const int nCh = (Nn + 1 + 511) / 512;

    if (ws_size >= need_csr) {
        int*    cnt     = (int*)   (ws + o_cnt);
        float*  msg     = (float*) (ws + o_msg);
        float*  coord   = (float*) (ws + o_coord);
        int*    srcs    = (int*)   (ws + o_srcs);
        int*    dsts    = (int*)   (ws + o_dsts);
        float4* rel4    = (float4*)(ws + o_rel);
        __bf16* PB      = (__bf16*)(ws + o_pb);
        int*    off     = (int*)   (ws + o_off);
        int*    cursor  = (int*)   (ws + o_cur);
        int*    bsum    = (int*)   (ws + o_bsum);
        int*    base    = (int*)   (ws + o_base);
        int*    flags   = (int*)   (ws + o_flags);

        detect_kernel<<<1, 256, 0, stream>>>((const unsigned short*)h, (const int*)ei0, flags);
        hipMemsetAsync(ws + o_cnt, 0, zero_end - o_cnt, stream);
        histd_kernel<<<(Ee + 511)/512, 512, 0, stream>>>(ei0, cnt, flags, Ee);
        scanA_kernel<<<nCh, 512, 0, stream>>>(cnt, bsum, Nn);
        scanB_kernel<<<1, 64, 0, stream>>>(bsum, base, nCh);
        scanC_kernel<<<nCh, 512, 0, stream>>>(cnt, base, off, cursor, Nn);
        scatgeo_kernel<<<(Ee + 511)/512, 512, 0, stream>>>(ei0, cursor, srcs, dsts,
                                                           rel4, x, flags, Ee);
        proj_kernel<<<512, 512, 0, stream>>>(h, We1, be1, flags, PB, Nn);

        // barrier-free per-wave edge pipeline: 1 block/CU, 16 waves, 4/SIMD
        egnn_edge_wave_kernel<<<256, 1024, 0, stream>>>(PB, srcs, dsts, rel4,
                                                        We1, We2, be2, Wc1, bc1, Wc2,
                                                        flags, msg, coord, Ee);

        egnn_node_kernel<<<1024, 512, 0, stream>>>(h, msg, Wn1, bn1, Wn2, bn2,
                                                   flags, d_out, x, coord,
                                                   (size_t)Nn*H, 1, Nn);
    } else {
        // fallback: proven R2 atomic path
        float* msg_agg   = (float*)ws;
        float* coord_agg = (float*)(ws + (size_t)Nn*H*4);
        int*   ei        = (int*)  (ws + (size_t)Nn*H*4 + (size_t)Nn*3*4);
        int*   flags     = (int*)  (ws + (size_t)Nn*H*4 + (size_t)Nn*3*4 + (size_t)2*Ee*4);

        detect_kernel<<<1, 256, 0, stream>>>((const unsigned short*)h, (const int*)ei0, flags);
        cvt_ei_kernel<<<(2*Ee + 255)/256, 256, 0, stream>>>(ei0, ei, 2*Ee, flags);
        hipMemsetAsync(msg_agg,   0, (size_t)Nn*H*4, stream);
        hipMemsetAsync(coord_agg, 0, (size_t)Nn*3*4, stream);
        egnn_edge_kernel<<<1024, 512, 0, stream>>>(h, x, ei, We1, be1, We2, be2,
                                                   Wc1, bc1, Wc2, flags,
                                                   msg_agg, coord_agg, Nn, Ee);
        egnn_node_kernel<<<512, 512, 0, stream>>>(h, msg_agg, Wn1, bn1, Wn2, bn2,
                                                  flags, d_out, x, coord_agg,
                                                  (size_t)Nn*H, 0, Nn);
        egnn_x_kernel<<<(Nn*3 + 255)/256, 256, 0, stream>>>(x, coord_agg, flags, d_out,
                                                            (size_t)Nn*H, Nn*3);
    }
}

// Round 5
// 669.686 us; speedup vs baseline: 2.0184x; 2.0184x over previous
//
#include <hip/hip_runtime.h>

#define H 128

typedef __bf16 bf8_t __attribute__((ext_vector_type(8)));
typedef __bf16 bf2_t __attribute__((ext_vector_type(2)));
typedef float  f4_t  __attribute__((ext_vector_type(4)));

#define MFMA16(a, b, c) __builtin_amdgcn_mfma_f32_16x16x32_bf16((a), (b), (c), 0, 0, 0)

__device__ __forceinline__ float silu_f(float v) {
    return v * (1.0f / (1.0f + __expf(-v)));
}

// LDS-only barrier: does NOT drain vmcnt, so global prefetch stays in flight.
__device__ __forceinline__ void bar_lds() {
    asm volatile("s_waitcnt lgkmcnt(0)\ns_barrier" ::: "memory");
}

__device__ __forceinline__ float wload(const void* p, int idx, bool f32) {
    return f32 ? ((const float*)p)[idx] : (float)((const __bf16*)p)[idx];
}

__device__ __forceinline__ bf8_t hload8(const void* p, size_t off, bool f32) {
    bf8_t v;
    if (f32) {
        const float4* q = (const float4*)((const float*)p + off);
        const float4 a = q[0], b = q[1];
        v[0]=(__bf16)a.x; v[1]=(__bf16)a.y; v[2]=(__bf16)a.z; v[3]=(__bf16)a.w;
        v[4]=(__bf16)b.x; v[5]=(__bf16)b.y; v[6]=(__bf16)b.z; v[7]=(__bf16)b.w;
    } else {
        v = *(const bf8_t*)((const __bf16*)p + off);
    }
    return v;
}

__device__ __forceinline__ int eidx(const void* ei, int i, bool i64) {
    return i64 ? (int)((const long long*)ei)[i] : ((const int*)ei)[i];
}

// ---------------------------------------------------------------------------
// dtype detection
// ---------------------------------------------------------------------------
__global__ void detect_kernel(const unsigned short* __restrict__ hraw,
                              const int* __restrict__ eiraw, int* __restrict__ flags)
{
    __shared__ int s_nf, s_oddnz;
    if (threadIdx.x == 0) { s_nf = 0; s_oddnz = 0; }
    __syncthreads();
    int nf = 0;
    for (int i = threadIdx.x; i < 16384; i += blockDim.x) {
        const unsigned short u = hraw[i];
        if (((u >> 7) & 0xFF) == 0xFF) nf++;
    }
    int onz = 0;
    for (int i = threadIdx.x; i < 512; i += blockDim.x) {
        if (eiraw[2*i + 1] != 0) onz++;
    }
    if (nf)  atomicAdd(&s_nf, nf);
    if (onz) atomicAdd(&s_oddnz, onz);
    __syncthreads();
    if (threadIdx.x == 0) {
        flags[0] = (s_nf > 0) ? 1 : 0;
        flags[1] = (s_oddnz == 0) ? 1 : 0;
    }
}

// ---------------------------------------------------------------------------
// CSR build: dst histogram (raw ei) -> scan -> scatter+geometry (fused)
// ---------------------------------------------------------------------------
__global__ void histd_kernel(const void* __restrict__ ei, int* __restrict__ cnt,
                             const int* __restrict__ flags, int Ee)
{
    const int e = blockIdx.x*blockDim.x + threadIdx.x;
    if (e < Ee) atomicAdd(&cnt[eidx(ei, Ee + e, flags[1] != 0)], 1);
}

__global__ void scanA_kernel(const int* __restrict__ cnt, int* __restrict__ bsum, int Nn)
{
    __shared__ int s[512];
    const int gi = blockIdx.x*512 + threadIdx.x;
    s[threadIdx.x] = (gi < Nn) ? cnt[gi] : 0;
    __syncthreads();
    for (int off = 256; off > 0; off >>= 1) {
        if (threadIdx.x < off) s[threadIdx.x] += s[threadIdx.x + off];
        __syncthreads();
    }
    if (threadIdx.x == 0) bsum[blockIdx.x] = s[0];
}

__global__ void scanB_kernel(int* __restrict__ bsum, int* __restrict__ base, int nCh)
{
    if (threadIdx.x == 0) {
        int acc = 0;
        for (int b = 0; b < nCh; ++b) { base[b] = acc; acc += bsum[b]; }
    }
}

__global__ void scanC_kernel(const int* __restrict__ cnt, const int* __restrict__ base,
                             int* __restrict__ off, int* __restrict__ cursor, int Nn)
{
    __shared__ int s[512];
    const int i  = threadIdx.x;
    const int gi = blockIdx.x*512 + i;
    const int v  = (gi < Nn) ? cnt[gi] : 0;
    s[i] = v;
    __syncthreads();
    for (int o = 1; o < 512; o <<= 1) {
        const int t = (i >= o) ? s[i - o] : 0;
        __syncthreads();
        s[i] += t;
        __syncthreads();
    }
    const int excl = s[i] - v;
    if (gi <= Nn) {
        const int val = base[blockIdx.x] + excl;
        off[gi] = val;
        if (gi < Nn) cursor[gi] = val;
    }
}

// scatter + geometry: compute sorted slot, write srcs/dsts/rel4 at slot
__global__ void scatgeo_kernel(const void* __restrict__ ei, int* __restrict__ cursor,
                               int* __restrict__ srcs, int* __restrict__ dsts,
                               float4* __restrict__ rel4, const void* __restrict__ x,
                               const int* __restrict__ flags, int Ee)
{
    const int e = blockIdx.x*blockDim.x + threadIdx.x;
    if (e >= Ee) return;
    const bool i64 = flags[1] != 0;
    const bool f32 = flags[0] != 0;
    const int s = eidx(ei, e, i64);
    const int d = eidx(ei, Ee + e, i64);
    const int p = atomicAdd(&cursor[d], 1);
    srcs[p] = s;
    dsts[p] = d;
    float r[3];
    #pragma unroll
    for (int c = 0; c < 3; ++c)
        r[c] = wload(x, s*3 + c, f32) - wload(x, d*3 + c, f32);
    float4 o; o.x = r[0]; o.y = r[1]; o.z = r[2];
    o.w = r[0]*r[0] + r[1]*r[1] + r[2]*r[2];
    rel4[p] = o;
}

// ---------------------------------------------------------------------------
// Projection kernel: PB[n][0:128]   = (h @ We1[0:128])[n]
//                    PB[n][128:256] = (h @ We1[128:256])[n] + be1
// ---------------------------------------------------------------------------
__global__ __launch_bounds__(512, 2)
void proj_kernel(const void* __restrict__ h, const void* __restrict__ We1,
                 const void* __restrict__ be1, const int* __restrict__ flags,
                 __bf16* __restrict__ PB, int Nn)
{
    const bool f32 = flags[0] != 0;
    const int tid  = threadIdx.x;
    const int wv   = tid >> 6;
    const int lane = tid & 63;
    const int quad = lane >> 4;
    const int l15  = lane & 15;

    bf8_t bW[4][2];
    float bias[2];
    #pragma unroll
    for (int t = 0; t < 2; ++t) {
        const int n    = wv*32 + t*16 + l15;
        const int rb   = (n < 128) ? 0 : 128;
        const int col  = n & 127;
        #pragma unroll
        for (int kc = 0; kc < 4; ++kc) {
            bf8_t v;
            #pragma unroll
            for (int j = 0; j < 8; ++j)
                v[j] = (__bf16)wload(We1, (rb + kc*32 + quad*8 + j)*H + col, f32);
            bW[kc][t] = v;
        }
        bias[t] = (n < 128) ? 0.f : wload(be1, col, f32);
    }

    __shared__ __bf16 s_h[32*136];

    const int tiles = (Nn + 31) >> 5;
    for (int tile = blockIdx.x; tile < tiles; tile += gridDim.x) {
        const int nb = tile << 5;
        __syncthreads();
        {
            const int m = tid >> 4, c = tid & 15;
            int node = nb + m; if (node >= Nn) node = Nn - 1;
            *(bf8_t*)&s_h[m*136 + c*8] = hload8(h, (size_t)node*H + c*8, f32);
        }
        __syncthreads();

        f4_t acc[2][2];
        #pragma unroll
        for (int mm = 0; mm < 2; ++mm)
            #pragma unroll
            for (int t = 0; t < 2; ++t) acc[mm][t] = (f4_t){0.f,0.f,0.f,0.f};
        #pragma unroll
        for (int kc = 0; kc < 4; ++kc) {
            #pragma unroll
            for (int mm = 0; mm < 2; ++mm) {
                const bf8_t a = *(const bf8_t*)&s_h[(mm*16 + l15)*136 + quad*8 + kc*32];
                acc[mm][0] = MFMA16(a, bW[kc][0], acc[mm][0]);
                acc[mm][1] = MFMA16(a, bW[kc][1], acc[mm][1]);
            }
        }
        #pragma unroll
        for (int mm = 0; mm < 2; ++mm)
            #pragma unroll
            for (int i = 0; i < 4; ++i) {
                const int row = nb + mm*16 + quad*4 + i;
                if (row < Nn) {
                    #pragma unroll
                    for (int t = 0; t < 2; ++t)
                        PB[(size_t)row*256 + wv*32 + t*16 + l15] =
                            (__bf16)(acc[mm][t][i] + bias[t]);
                }
            }
    }
}

// ---------------------------------------------------------------------------
// Edge kernel (R6-verified structure + T5 setprio): 64-edge dst-sorted tiles,
// 3 lgkm-only barriers per tile. Layer 1 = gather PB rows + add + d2*w1d +
// silu. Layers 2/3 = MFMA (setprio-wrapped). In-kernel segmented reduction of
// m_ij (msg) and rel*cw (coord) over sorted dst-runs: interior runs -> plain
// stores (exactly-once), tile-boundary runs -> f32 atomics.
// ---------------------------------------------------------------------------
__global__ __launch_bounds__(512, 2)
void egnn_edge_pipe_kernel(const __bf16* __restrict__ PB,
                           const int* __restrict__ srcs, const int* __restrict__ dsts,
                           const float4* __restrict__ rel4,
                           const void* __restrict__ We1,  // row 256 only (w1d)
                           const void* __restrict__ We2, const void* __restrict__ be2,
                           const void* __restrict__ Wc1, const void* __restrict__ bc1,
                           const void* __restrict__ Wc2, const int* __restrict__ flags,
                           float* __restrict__ msg, float* __restrict__ coord,
                           int Ee)
{
    const bool f32 = flags[0] != 0;
    const int tid  = threadIdx.x;
    const int wv   = tid >> 6;
    const int lane = tid & 63;
    const int quad = lane >> 4;
    const int l15  = lane & 15;
    const int mg   = wv >> 2;
    const int ng   = wv & 3;

    bf8_t bW2[4][2], bWc[4][2];
    float be2v[2], bc1v[2], wc2v[2];
    #pragma unroll
    for (int t = 0; t < 2; ++t) {
        const int n = ng*32 + t*16 + l15;
        #pragma unroll
        for (int kc = 0; kc < 4; ++kc) {
            bf8_t v, u;
            #pragma unroll
            for (int j = 0; j < 8; ++j) {
                v[j] = (__bf16)wload(We2, (kc*32 + quad*8 + j)*H + n, f32);
                u[j] = (__bf16)wload(Wc1, (kc*32 + quad*8 + j)*H + n, f32);
            }
            bW2[kc][t] = v;
            bWc[kc][t] = u;
        }
        be2v[t] = wload(be2, n, f32);
        bc1v[t] = wload(bc1, n, f32);
        wc2v[t] = wload(Wc2, n, f32);
    }

    const int em = tid >> 3;          // edge row 0..63
    const int ch = tid & 7;           // 2 column-chunks per thread
    float w1dA[8], w1dB[8];
    #pragma unroll
    for (int j = 0; j < 8; ++j) {
        w1dA[j] = wload(We1, 256*H + ch*8 + j, f32);
        w1dB[j] = wload(We1, 256*H + (ch+8)*8 + j, f32);
    }

    __shared__ __bf16 s_m1[64*136];
    __shared__ __bf16 s_m2[64*136];
    __shared__ float  s_cw[4*64];     // [ng][edge]
    __shared__ int    s_dst[2][64];
    __shared__ float4 s_rl[2][64];
    __shared__ float  s_pre[8][128];  // leading-run sum per 8-row group
    __shared__ float  s_suf[8][128];  // trailing-run sum per 8-row group
    __shared__ int    s_wh[8];        // group is a single run

    const int tiles = (Ee + 63) >> 6;
    const float* rw = (const float*)rel4;

    bf8_t rA0, rA1, rB0, rB1;
    float d2cur, d2nxt;
    int   s_n, d_n, d_c;
    float4 r4c, r4n;
    {
        int e0 = blockIdx.x*64 + em; if (e0 >= Ee) e0 = Ee - 1;
        const int sc = srcs[e0], dc = dsts[e0];
        d_c = dc;
        d2cur = rw[(size_t)e0*4 + 3];
        if (ch == 0) r4c = rel4[e0];
        rA0 = *(const bf8_t*)(PB + (size_t)sc*256 + ch*8);
        rA1 = *(const bf8_t*)(PB + (size_t)sc*256 + (ch+8)*8);
        rB0 = *(const bf8_t*)(PB + (size_t)dc*256 + 128 + ch*8);
        rB1 = *(const bf8_t*)(PB + (size_t)dc*256 + 128 + (ch+8)*8);
        const int t1 = blockIdx.x + gridDim.x;
        const int tt = (t1 < tiles) ? t1 : blockIdx.x;
        int e1 = tt*64 + em; if (e1 >= Ee) e1 = Ee - 1;
        s_n = srcs[e1]; d_n = dsts[e1]; d2nxt = rw[(size_t)e1*4 + 3];
        if (ch == 0) r4n = rel4[e1];
    }

    int li = 0;
    for (int t = blockIdx.x; t < tiles; t += gridDim.x, ++li) {
        const int sb = li & 1;
        // ---- stage layer-1 output + dst/rel staging ----
        {
            bf8_t o0, o1;
            #pragma unroll
            for (int j = 0; j < 8; ++j) {
                const float f0 = (float)rA0[j] + (float)rB0[j] + d2cur*w1dA[j];
                const float f1 = (float)rA1[j] + (float)rB1[j] + d2cur*w1dB[j];
                o0[j] = (__bf16)silu_f(f0);
                o1[j] = (__bf16)silu_f(f1);
            }
            *(bf8_t*)&s_m1[em*136 + ch*8]       = o0;
            *(bf8_t*)&s_m1[em*136 + (ch+8)*8]   = o1;
            if (ch == 0) { s_dst[sb][em] = d_c; s_rl[sb][em] = r4c; }
        }
        // ---- prefetch next tile ----
        {
            const int sc = s_n, dc2 = d_n;
            rA0 = *(const bf8_t*)(PB + (size_t)sc*256 + ch*8);
            rA1 = *(const bf8_t*)(PB + (size_t)sc*256 + (ch+8)*8);
            rB0 = *(const bf8_t*)(PB + (size_t)dc2*256 + 128 + ch*8);
            rB1 = *(const bf8_t*)(PB + (size_t)dc2*256 + 128 + (ch+8)*8);
            d_c = d_n; d2cur = d2nxt;
            if (ch == 0) r4c = r4n;
            const int t2 = t + 2*gridDim.x;
            const int tt = (t2 < tiles) ? t2 : t;
            int e2 = tt*64 + em; if (e2 >= Ee) e2 = Ee - 1;
            s_n = srcs[e2]; d_n = dsts[e2]; d2nxt = rw[(size_t)e2*4 + 3];
            if (ch == 0) r4n = rel4[e2];
        }
        bar_lds();

        // ---- layer 2: m2 = silu(m1 @ We2 + be2) ----
        {
            f4_t a2[2][2];
            #pragma unroll
            for (int mm = 0; mm < 2; ++mm)
                #pragma unroll
                for (int h2 = 0; h2 < 2; ++h2) a2[mm][h2] = (f4_t){0.f,0.f,0.f,0.f};
            __builtin_amdgcn_s_setprio(1);
            #pragma unroll
            for (int kc = 0; kc < 4; ++kc) {
                #pragma unroll
                for (int mm = 0; mm < 2; ++mm) {
                    const bf8_t a = *(const bf8_t*)&s_m1[(mg*32 + mm*16 + l15)*136 + quad*8 + kc*32];
                    a2[mm][0] = MFMA16(a, bW2[kc][0], a2[mm][0]);
                    a2[mm][1] = MFMA16(a, bW2[kc][1], a2[mm][1]);
                }
            }
            __builtin_amdgcn_s_setprio(0);
            #pragma unroll
            for (int mm = 0; mm < 2; ++mm)
                #pragma unroll
                for (int i = 0; i < 4; ++i) {
                    const int m = mg*32 + mm*16 + quad*4 + i;
                    s_m2[m*136 + ng*32 + l15]      = (__bf16)silu_f(a2[mm][0][i] + be2v[0]);
                    s_m2[m*136 + ng*32 + 16 + l15] = (__bf16)silu_f(a2[mm][1][i] + be2v[1]);
                }
        }
        bar_lds();

        // ---- layer 3: coord head partials ----
        {
            f4_t a3[2][2];
            #pragma unroll
            for (int mm = 0; mm < 2; ++mm)
                #pragma unroll
                for (int h2 = 0; h2 < 2; ++h2) a3[mm][h2] = (f4_t){0.f,0.f,0.f,0.f};
            __builtin_amdgcn_s_setprio(1);
            #pragma unroll
            for (int kc = 0; kc < 4; ++kc) {
                #pragma unroll
                for (int mm = 0; mm < 2; ++mm) {
                    const bf8_t a = *(const bf8_t*)&s_m2[(mg*32 + mm*16 + l15)*136 + quad*8 + kc*32];
                    a3[mm][0] = MFMA16(a, bWc[kc][0], a3[mm][0]);
                    a3[mm][1] = MFMA16(a, bWc[kc][1], a3[mm][1]);
                }
            }
            __builtin_amdgcn_s_setprio(0);
            float p[2][4];
            #pragma unroll
            for (int mm = 0; mm < 2; ++mm)
                #pragma unroll
                for (int i = 0; i < 4; ++i) {
                    const float v0 = silu_f(a3[mm][0][i] + bc1v[0]);
                    const float v1 = silu_f(a3[mm][1][i] + bc1v[1]);
                    p[mm][i] = v0*wc2v[0] + v1*wc2v[1];
                }
            #pragma unroll
            for (int off = 1; off < 16; off <<= 1)
                #pragma unroll
                for (int mm = 0; mm < 2; ++mm)
                    #pragma unroll
                    for (int i = 0; i < 4; ++i) p[mm][i] += __shfl_xor(p[mm][i], off, 64);
            if (l15 == 0) {
                #pragma unroll
                for (int mm = 0; mm < 2; ++mm)
                    #pragma unroll
                    for (int i = 0; i < 4; ++i)
                        s_cw[ng*64 + (mg*32 + mm*16 + quad*4 + i)] = p[mm][i];
            }
        }

        // ---- msg per-group scan: wave wv owns rows wv*8..wv*8+7, all 128
        //      cols (2 adjacent cols per lane, one b32 LDS read per row).
        //      Run-boundary control flow is wave-uniform (readfirstlane).
        {
            const int rbase = wv << 3;
            const int c0    = lane << 1;
            int   curd = __builtin_amdgcn_readfirstlane(s_dst[sb][rbase]);
            float ax = 0.f, ay = 0.f;
            float px = 0.f, py = 0.f;
            int   predone = 0;
            #pragma unroll
            for (int i = 0; i < 8; ++i) {
                const int d = __builtin_amdgcn_readfirstlane(s_dst[sb][rbase + i]);
                const bf2_t v = *(const bf2_t*)&s_m2[(rbase + i)*136 + c0];
                const float vx = (float)v[0], vy = (float)v[1];
                if (d != curd) {
                    if (!predone) { px = ax; py = ay; predone = 1; }
                    else {
                        float2 st; st.x = ax; st.y = ay;
                        *(float2*)&msg[(size_t)curd*H + c0] = st;   // interior run
                    }
                    curd = d; ax = vx; ay = vy;
                } else { ax += vx; ay += vy; }
            }
            s_pre[wv][c0]   = px;  s_pre[wv][c0+1] = py;
            s_suf[wv][c0]   = ax;  s_suf[wv][c0+1] = ay;
            if (lane == 0) s_wh[wv] = !predone;
        }
        bar_lds();

        // ---- msg merge across 8 row-groups (waves 2-3, 1 col/lane) ----
        if (tid >= 128 && tid < 256) {
            const int c = tid - 128;
            int   curd2 = __builtin_amdgcn_readfirstlane(s_dst[sb][0]);
            float cur   = 0.f;
            int   first = 1;
            #pragma unroll
            for (int gg = 0; gg < 8; ++gg) {
                const int F  = __builtin_amdgcn_readfirstlane(s_dst[sb][gg*8]);
                const int L  = __builtin_amdgcn_readfirstlane(s_dst[sb][gg*8 + 7]);
                const int wh = __builtin_amdgcn_readfirstlane(s_wh[gg]);
                const float preg = s_pre[gg][c];
                const float sufg = s_suf[gg][c];
                if (F != curd2) {
                    if (first) atomicAdd(&msg[(size_t)curd2*H + c], cur);
                    else       msg[(size_t)curd2*H + c] = cur;
                    first = 0; curd2 = F; cur = 0.f;
                }
                if (wh) {
                    cur += sufg;
                } else {
                    cur += preg;
                    if (first) atomicAdd(&msg[(size_t)curd2*H + c], cur);
                    else       msg[(size_t)curd2*H + c] = cur;
                    first = 0; curd2 = L; cur = sufg;
                }
            }
            atomicAdd(&msg[(size_t)curd2*H + c], cur);  // last run: boundary
        }

        // ---- coord segmented scan (wave 0): cw per edge, runs over dsts ----
        if (tid < 64) {
            const int e = tid;
            const float cwv = s_cw[e] + s_cw[64 + e] + s_cw[128 + e] + s_cw[192 + e];
            const float4 r = s_rl[sb][e];
            const int d = s_dst[sb][e];
            float vx = r.x*cwv, vy = r.y*cwv, vz = r.z*cwv;
            int   cn = 1;
            #pragma unroll
            for (int k = 1; k < 64; k <<= 1) {
                const int   dk = __shfl_up(d,  k, 64);
                const float xk = __shfl_up(vx, k, 64);
                const float yk = __shfl_up(vy, k, 64);
                const float zk = __shfl_up(vz, k, 64);
                const int   ck = __shfl_up(cn, k, 64);
                if (e >= k && dk == d) { vx += xk; vy += yk; vz += zk; cn += ck; }
            }
            const int dnx = __shfl_down(d, 1, 64);
            const bool runend = (e == 63) || (dnx != d);
            if (runend) {
                const int rs = e - cn + 1;
                if (rs == 0 || e == 63) {
                    atomicAdd(&coord[(size_t)d*3 + 0], vx);
                    atomicAdd(&coord[(size_t)d*3 + 1], vy);
                    atomicAdd(&coord[(size_t)d*3 + 2], vz);
                } else {
                    coord[(size_t)d*3 + 0] = vx;
                    coord[(size_t)d*3 + 1] = vy;
                    coord[(size_t)d*3 + 2] = vz;
                }
            }
        }
    }
}

// ---------------------------------------------------------------------------
// Node kernel: h_out = h + silu([h | msg] @ Wn1 + bn1) @ Wn2 + bn2
// msg is f32. Optionally also emits x_out = x + coord (do_x).
// ---------------------------------------------------------------------------
__global__ __launch_bounds__(512, 2)
void egnn_node_kernel(const void* __restrict__ h, const float* __restrict__ msg,
                      const void* __restrict__ Wn1, const void* __restrict__ bn1,
                      const void* __restrict__ Wn2, const void* __restrict__ bn2,
                      const int* __restrict__ flags, void* __restrict__ h_out,
                      const void* __restrict__ x, const float* __restrict__ coord,
                      size_t obase, int do_x, int Nn)
{
    const bool f32 = flags[0] != 0;
    const int tid  = threadIdx.x;
    const int wv   = tid >> 6;
    const int lane = tid & 63;
    const int quad = lane >> 4;
    const int l15  = lane & 15;
    const int mg   = wv >> 2;
    const int ng   = wv & 3;

    bf8_t bW1[8][2];
    bf8_t bW2[4][2];
    float b1v[2], b2v[2];
    #pragma unroll
    for (int t = 0; t < 2; ++t) {
        const int n = ng*32 + t*16 + l15;
        #pragma unroll
        for (int kc = 0; kc < 8; ++kc) {
            bf8_t v;
            #pragma unroll
            for (int j = 0; j < 8; ++j) v[j] = (__bf16)wload(Wn1, (kc*32 + quad*8 + j)*H + n, f32);
            bW1[kc][t] = v;
        }
        #pragma unroll
        for (int kc = 0; kc < 4; ++kc) {
            bf8_t v;
            #pragma unroll
            for (int j = 0; j < 8; ++j) v[j] = (__bf16)wload(Wn2, (kc*32 + quad*8 + j)*H + n, f32);
            bW2[kc][t] = v;
        }
        b1v[t] = wload(bn1, n, f32);
        b2v[t] = wload(bn2, n, f32);
    }

    __shared__ __bf16 s_in[32*264];
    __shared__ __bf16 s_t1[32*136];

    const int tiles = (Nn + 31) >> 5;
    for (int tile = blockIdx.x; tile < tiles; tile += gridDim.x) {
        const int nb = tile << 5;
        __syncthreads();
        #pragma unroll
        for (int r = 0; r < 2; ++r) {
            const int idx = tid + r*512;
            const int m = idx >> 5, c = idx & 31;
            int node = nb + m;
            if (node >= Nn) node = Nn - 1;
            if (c < 16) {
                *(bf8_t*)&s_in[m*264 + c*8] = hload8(h, (size_t)node*H + c*8, f32);
            } else {
                const float4* mp = (const float4*)(msg + (size_t)node*H + (c - 16)*8);
                const float4 v0 = mp[0], v1 = mp[1];
                __bf16* d = &s_in[m*264 + c*8];
                d[0] = (__bf16)v0.x; d[1] = (__bf16)v0.y; d[2] = (__bf16)v0.z; d[3] = (__bf16)v0.w;
                d[4] = (__bf16)v1.x; d[5] = (__bf16)v1.y; d[6] = (__bf16)v1.z; d[7] = (__bf16)v1.w;
            }
        }
        // x_out epilogue (independent of LDS)
        if (do_x && tid < 96) {
            const int m = tid / 3, c = tid - m*3;
            const int node = nb + m;
            if (node < Nn) {
                const float xv = wload(x, node*3 + c, f32);
                const float o = xv + coord[(size_t)node*3 + c];
                if (f32) ((float*)h_out)[obase + (size_t)node*3 + c] = o;
                else     ((__bf16*)h_out)[obase + (size_t)node*3 + c] = (__bf16)o;
            }
        }
        __syncthreads();

        {
            f4_t a0 = {0.f,0.f,0.f,0.f}, a1 = {0.f,0.f,0.f,0.f};
            const int abase = (mg*16 + l15)*264 + quad*8;
            #pragma unroll
            for (int kc = 0; kc < 8; ++kc) {
                const bf8_t a = *(const bf8_t*)&s_in[abase + kc*32];
                a0 = MFMA16(a, bW1[kc][0], a0);
                a1 = MFMA16(a, bW1[kc][1], a1);
            }
            #pragma unroll
            for (int i = 0; i < 4; ++i) {
                const int m = mg*16 + quad*4 + i;
                s_t1[m*136 + ng*32 + l15]      = (__bf16)silu_f(a0[i] + b1v[0]);
                s_t1[m*136 + ng*32 + 16 + l15] = (__bf16)silu_f(a1[i] + b1v[1]);
            }
        }
        __syncthreads();

        {
            f4_t a0 = {0.f,0.f,0.f,0.f}, a1 = {0.f,0.f,0.f,0.f};
            const int abase = (mg*16 + l15)*136 + quad*8;
            #pragma unroll
            for (int kc = 0; kc < 4; ++kc) {
                const bf8_t a = *(const bf8_t*)&s_t1[abase + kc*32];
                a0 = MFMA16(a, bW2[kc][0], a0);
                a1 = MFMA16(a, bW2[kc][1], a1);
            }
            #pragma unroll
            for (int i = 0; i < 4; ++i) {
                const int node = nb + mg*16 + quad*4 + i;
                if (node < Nn) {
                    const int n0 = ng*32 + l15, n1 = n0 + 16;
                    const size_t i0 = (size_t)node*H + n0, i1 = (size_t)node*H + n1;
                    const float h0 = f32 ? ((const float*)h)[i0] : (float)((const __bf16*)h)[i0];
                    const float h1 = f32 ? ((const float*)h)[i1] : (float)((const __bf16*)h)[i1];
                    const float o0 = a0[i] + b2v[0] + h0;
                    const float o1 = a1[i] + b2v[1] + h1;
                    if (f32) {
                        ((float*)h_out)[i0] = o0;
                        ((float*)h_out)[i1] = o1;
                    } else {
                        ((__bf16*)h_out)[i0] = (__bf16)o0;
                        ((__bf16*)h_out)[i1] = (__bf16)o1;
                    }
                }
            }
        }
    }
}

// ---------------------------------------------------------------------------
// Fallback (R2 atomic path)
// ---------------------------------------------------------------------------
__global__ void cvt_ei_kernel(const void* __restrict__ src, int* __restrict__ dst,
                              int n, const int* __restrict__ flags)
{
    const int i = blockIdx.x*blockDim.x + threadIdx.x;
    if (i >= n) return;
    dst[i] = flags[1] ? (int)((const long long*)src)[i] : ((const int*)src)[i];
}

__global__ __launch_bounds__(512, 2)
void egnn_edge_kernel(const void* __restrict__ h, const void* __restrict__ x,
                      const int* __restrict__ ei,
                      const void* __restrict__ We1, const void* __restrict__ be1,
                      const void* __restrict__ We2, const void* __restrict__ be2,
                      const void* __restrict__ Wc1, const void* __restrict__ bc1,
                      const void* __restrict__ Wc2, const int* __restrict__ flags,
                      float* __restrict__ msg_agg, float* __restrict__ coord_agg,
                      int Nn, int Ee)
{
    const bool f32 = flags[0] != 0;
    const int tid  = threadIdx.x;
    const int wv   = tid >> 6;
    const int lane = tid & 63;
    const int quad = lane >> 4;
    const int l15  = lane & 15;
    const int mg   = wv >> 2;
    const int ng   = wv & 3;

    bf8_t bW1[8][2];
    bf8_t bW2[4][2];
    bf8_t bWc[4][2];
    float be1v[2], be2v[2], bc1v[2], w1dv[2], wc2v[2];
    #pragma unroll
    for (int t = 0; t < 2; ++t) {
        const int n = ng*32 + t*16 + l15;
        #pragma unroll
        for (int kc = 0; kc < 8; ++kc) {
            bf8_t v;
            #pragma unroll
            for (int j = 0; j < 8; ++j) v[j] = (__bf16)wload(We1, (kc*32 + quad*8 + j)*H + n, f32);
            bW1[kc][t] = v;
        }
        #pragma unroll
        for (int kc = 0; kc < 4; ++kc) {
            bf8_t v, u;
            #pragma unroll
            for (int j = 0; j < 8; ++j) {
                v[j] = (__bf16)wload(We2, (kc*32 + quad*8 + j)*H + n, f32);
                u[j] = (__bf16)wload(Wc1, (kc*32 + quad*8 + j)*H + n, f32);
            }
            bW2[kc][t] = v;
            bWc[kc][t] = u;
        }
        be1v[t] = wload(be1, n, f32);
        be2v[t] = wload(be2, n, f32);
        bc1v[t] = wload(bc1, n, f32);
        w1dv[t] = wload(We1, 256*H + n, f32);
        wc2v[t] = wload(Wc2, n, f32);
    }

    __shared__ __bf16 s_in[32*264];
    __shared__ __bf16 s_m1[32*136];
    __shared__ __bf16 s_m2[32*136];
    __shared__ float  s_rel[32*3];
    __shared__ float  s_dist[32];
    __shared__ int    s_dstv[32];
    __shared__ float  s_cw[32*4];

    const int tiles = Ee >> 5;
    for (int tile = blockIdx.x; tile < tiles; tile += gridDim.x) {
        const int ebase = tile << 5;
        __syncthreads();

        if (tid < 32) {
            const int e  = ebase + tid;
            const int sn = ei[e];
            const int dn = ei[Ee + e];
            s_dstv[tid] = dn;
            float d2 = 0.f;
            #pragma unroll
            for (int c = 0; c < 3; ++c) {
                float r;
                if (f32) r = ((const float*)x)[sn*3 + c] - ((const float*)x)[dn*3 + c];
                else     r = (float)((const __bf16*)x)[sn*3 + c] - (float)((const __bf16*)x)[dn*3 + c];
                s_rel[tid*3 + c] = r;
                d2 += r*r;
            }
            s_dist[tid] = d2;
        }
        #pragma unroll
        for (int r = 0; r < 2; ++r) {
            const int idx = tid + r*512;
            const int m = idx >> 5, c = idx & 31;
            const int e = ebase + m;
            const int node = (c < 16) ? ei[e] : ei[Ee + e];
            *(bf8_t*)&s_in[m*264 + c*8] = hload8(h, (size_t)node*H + (c & 15)*8, f32);
        }
        __syncthreads();

        {
            f4_t a0 = {0.f,0.f,0.f,0.f}, a1 = {0.f,0.f,0.f,0.f};
            const int abase = (mg*16 + l15)*264 + quad*8;
            #pragma unroll
            for (int kc = 0; kc < 8; ++kc) {
                const bf8_t a = *(const bf8_t*)&s_in[abase + kc*32];
                a0 = MFMA16(a, bW1[kc][0], a0);
                a1 = MFMA16(a, bW1[kc][1], a1);
            }
            #pragma unroll
            for (int i = 0; i < 4; ++i) {
                const int m = mg*16 + quad*4 + i;
                const float d2 = s_dist[m];
                s_m1[m*136 + ng*32 + l15]      = (__bf16)silu_f(a0[i] + d2*w1dv[0] + be1v[0]);
                s_m1[m*136 + ng*32 + 16 + l15] = (__bf16)silu_f(a1[i] + d2*w1dv[1] + be1v[1]);
            }
        }
        __syncthreads();

        {
            f4_t a0 = {0.f,0.f,0.f,0.f}, a1 = {0.f,0.f,0.f,0.f};
            const int abase = (mg*16 + l15)*136 + quad*8;
            #pragma unroll
            for (int kc = 0; kc < 4; ++kc) {
                const bf8_t a = *(const bf8_t*)&s_m1[abase + kc*32];
                a0 = MFMA16(a, bW2[kc][0], a0);
                a1 = MFMA16(a, bW2[kc][1], a1);
            }
            #pragma unroll
            for (int i = 0; i < 4; ++i) {
                const int m = mg*16 + quad*4 + i;
                const float v0 = silu_f(a0[i] + be2v[0]);
                const float v1 = silu_f(a1[i] + be2v[1]);
                s_m2[m*136 + ng*32 + l15]      = (__bf16)v0;
                s_m2[m*136 + ng*32 + 16 + l15] = (__bf16)v1;
                const size_t db = (size_t)s_dstv[m]*H + ng*32 + l15;
                atomicAdd(&msg_agg[db],      v0);
                atomicAdd(&msg_agg[db + 16], v1);
            }
        }
        __syncthreads();

        {
            f4_t a0 = {0.f,0.f,0.f,0.f}, a1 = {0.f,0.f,0.f,0.f};
            const int abase = (mg*16 + l15)*136 + quad*8;
            #pragma unroll
            for (int kc = 0; kc < 4; ++kc) {
                const bf8_t a = *(const bf8_t*)&s_m2[abase + kc*32];
                a0 = MFMA16(a, bWc[kc][0], a0);
                a1 = MFMA16(a, bWc[kc][1], a1);
            }
            float p[4];
            #pragma unroll
            for (int i = 0; i < 4; ++i) {
                const float v0 = silu_f(a0[i] + bc1v[0]);
                const float v1 = silu_f(a1[i] + bc1v[1]);
                p[i] = v0*wc2v[0] + v1*wc2v[1];
            }
            #pragma unroll
            for (int off = 1; off < 16; off <<= 1) {
                #pragma unroll
                for (int i = 0; i < 4; ++i) p[i] += __shfl_xor(p[i], off, 64);
            }
            if (l15 == 0) {
                #pragma unroll
                for (int i = 0; i < 4; ++i)
                    s_cw[(mg*16 + quad*4 + i)*4 + ng] = p[i];
            }
        }
        __syncthreads();

        if (tid < 96) {
            const int m = tid / 3, c = tid - m*3;
            const float cw = s_cw[m*4 + 0] + s_cw[m*4 + 1] + s_cw[m*4 + 2] + s_cw[m*4 + 3];
            atomicAdd(&coord_agg[(size_t)s_dstv[m]*3 + c], s_rel[m*3 + c]*cw);
        }
    }
}

__global__ void egnn_x_kernel(const void* __restrict__ x, const float* __restrict__ coord_agg,
                              const int* __restrict__ flags, void* __restrict__ out,
                              size_t obase, int total)
{
    const bool f32 = flags[0] != 0;
    const int i = blockIdx.x*blockDim.x + threadIdx.x;
    if (i >= total) return;
    const float xv = f32 ? ((const float*)x)[i] : (float)((const __bf16*)x)[i];
    const float o = xv + coord_agg[i];
    if (f32) ((float*)out)[obase + i] = o;
    else     ((__bf16*)out)[obase + i] = (__bf16)o;
}

static inline size_t align256(size_t v) { return (v + 255) & ~(size_t)255; }

extern "C" void kernel_launch(void* const* d_in, const int* in_sizes, int n_in,
                              void* d_out, int out_size, void* d_ws, size_t ws_size,
                              hipStream_t stream)
{
    const void* h   = d_in[0];
    const void* x   = d_in[1];
    const void* ei0 = d_in[2];
    const void* We1 = d_in[3];
    const void* be1 = d_in[4];
    const void* We2 = d_in[5];
    const void* be2 = d_in[6];
    const void* Wc1 = d_in[7];
    const void* bc1 = d_in[8];
    const void* Wc2 = d_in[9];
    const void* Wn1 = d_in[10];
    const void* bn1 = d_in[11];
    const void* Wn2 = d_in[12];
    const void* bn2 = d_in[13];

    const int Nn = in_sizes[0] / H;   // 50000
    const int Ee = in_sizes[2] / 2;   // 640000

    char* ws = (char*)d_ws;
    size_t o = 0;
    // zero-init region: cnt | msg | coord (one memset)
    size_t o_cnt   = o; o = align256(o + (size_t)Nn*4);
    size_t o_msg   = o; o = align256(o + (size_t)Nn*H*4);      // msg_agg f32
    size_t o_coord = o; o = align256(o + (size_t)Nn*3*4);      // coord_agg f32
    const size_t zero_end = o;
    size_t o_srcs  = o; o = align256(o + (size_t)Ee*4);
    size_t o_dsts  = o; o = align256(o + (size_t)Ee*4);
    size_t o_rel   = o; o = align256(o + (size_t)Ee*16);       // rel4 (xyz, d2)
    size_t o_pb    = o; o = align256(o + (size_t)Nn*256*2);    // PB bf16 [N,256]
    size_t o_off   = o; o = align256(o + (size_t)(Nn+1)*4);
    size_t o_cur   = o; o = align256(o + (size_t)Nn*4);
    size_t o_bsum  = o; o = align256(o + 512*4);
    size_t o_base  = o; o = align256(o + 512*4);
    size_t o_flags = o; o = align256(o + 64);
    const size_t need_csr = o;

    const int nCh = (Nn + 1 + 511) / 512;

    if (ws_size >= need_csr) {
        int*    cnt     = (int*)   (ws + o_cnt);
        float*  msg     = (float*) (ws + o_msg);
        float*  coord   = (float*) (ws + o_coord);
        int*    srcs    = (int*)   (ws + o_srcs);
        int*    dsts    = (int*)   (ws + o_dsts);
        float4* rel4    = (float4*)(ws + o_rel);
        __bf16* PB      = (__bf16*)(ws + o_pb);
        int*    off     = (int*)   (ws + o_off);
        int*    cursor  = (int*)   (ws + o_cur);
        int*    bsum    = (int*)   (ws + o_bsum);
        int*    base    = (int*)   (ws + o_base);
        int*    flags   = (int*)   (ws + o_flags);

        detect_kernel<<<1, 256, 0, stream>>>((const unsigned short*)h, (const int*)ei0, flags);
        hipMemsetAsync(ws + o_cnt, 0, zero_end - o_cnt, stream);
        histd_kernel<<<(Ee + 511)/512, 512, 0, stream>>>(ei0, cnt, flags, Ee);
        scanA_kernel<<<nCh, 512, 0, stream>>>(cnt, bsum, Nn);
        scanB_kernel<<<1, 64, 0, stream>>>(bsum, base, nCh);
        scanC_kernel<<<nCh, 512, 0, stream>>>(cnt, base, off, cursor, Nn);
        scatgeo_kernel<<<(Ee + 511)/512, 512, 0, stream>>>(ei0, cursor, srcs, dsts,
                                                           rel4, x, flags, Ee);
        proj_kernel<<<512, 512, 0, stream>>>(h, We1, be1, flags, PB, Nn);

        // grid 512: ~20 tiles/block, 2 blocks/CU (R5-proven best config)
        egnn_edge_pipe_kernel<<<512, 512, 0, stream>>>(PB, srcs, dsts, rel4,
                                                       We1, We2, be2, Wc1, bc1, Wc2,
                                                       flags, msg, coord, Ee);

        egnn_node_kernel<<<1024, 512, 0, stream>>>(h, msg, Wn1, bn1, Wn2, bn2,
                                                   flags, d_out, x, coord,
                                                   (size_t)Nn*H, 1, Nn);
    } else {
        // fallback: proven R2 atomic path
        float* msg_agg   = (float*)ws;
        float* coord_agg = (float*)(ws + (size_t)Nn*H*4);
        int*   ei        = (int*)  (ws + (size_t)Nn*H*4 + (size_t)Nn*3*4);
        int*   flags     = (int*)  (ws + (size_t)Nn*H*4 + (size_t)Nn*3*4 + (size_t)2*Ee*4);

        detect_kernel<<<1, 256, 0, stream>>>((const unsigned short*)h, (const int*)ei0, flags);
        cvt_ei_kernel<<<(2*Ee + 255)/256, 256, 0, stream>>>(ei0, ei, 2*Ee, flags);
        hipMemsetAsync(msg_agg,   0, (size_t)Nn*H*4, stream);
        hipMemsetAsync(coord_agg, 0, (size_t)Nn*3*4, stream);
        egnn_edge_kernel<<<1024, 512, 0, stream>>>(h, x, ei, We1, be1, We2, be2,
                                                   Wc1, bc1, Wc2, flags,
                                                   msg_agg, coord_agg, Nn, Ee);
        egnn_node_kernel<<<512, 512, 0, stream>>>(h, msg_agg, Wn1, bn1, Wn2, bn2,
                                                  flags, d_out, x, coord_agg,
                                                  (size_t)Nn*H, 0, Nn);
        egnn_x_kernel<<<(Nn*3 + 255)/256, 256, 0, stream>>>(x, coord_agg, flags, d_out,
                                                            (size_t)Nn*H, Nn*3);
    }
}

// Round 6
// 645.675 us; speedup vs baseline: 2.0935x; 1.0372x over previous
//
#include <hip/hip_runtime.h>

#define H 128

typedef __bf16 bf8_t __attribute__((ext_vector_type(8)));
typedef __bf16 bf2_t __attribute__((ext_vector_type(2)));
typedef float  f4_t  __attribute__((ext_vector_type(4)));

#define MFMA16(a, b, c) __builtin_amdgcn_mfma_f32_16x16x32_bf16((a), (b), (c), 0, 0, 0)

__device__ __forceinline__ float silu_f(float v) {
    return v * (1.0f / (1.0f + __expf(-v)));
}

// LDS-only barrier: does NOT drain vmcnt, so global prefetch stays in flight.
__device__ __forceinline__ void bar_lds() {
    asm volatile("s_waitcnt lgkmcnt(0)\ns_barrier" ::: "memory");
}

__device__ __forceinline__ float wload(const void* p, int idx, bool f32) {
    return f32 ? ((const float*)p)[idx] : (float)((const __bf16*)p)[idx];
}

__device__ __forceinline__ bf8_t hload8(const void* p, size_t off, bool f32) {
    bf8_t v;
    if (f32) {
        const float4* q = (const float4*)((const float*)p + off);
        const float4 a = q[0], b = q[1];
        v[0]=(__bf16)a.x; v[1]=(__bf16)a.y; v[2]=(__bf16)a.z; v[3]=(__bf16)a.w;
        v[4]=(__bf16)b.x; v[5]=(__bf16)b.y; v[6]=(__bf16)b.z; v[7]=(__bf16)b.w;
    } else {
        v = *(const bf8_t*)((const __bf16*)p + off);
    }
    return v;
}

__device__ __forceinline__ int eidx(const void* ei, int i, bool i64) {
    return i64 ? (int)((const long long*)ei)[i] : ((const int*)ei)[i];
}

// ---------------------------------------------------------------------------
// dtype detection
// ---------------------------------------------------------------------------
__global__ void detect_kernel(const unsigned short* __restrict__ hraw,
                              const int* __restrict__ eiraw, int* __restrict__ flags)
{
    __shared__ int s_nf, s_oddnz;
    if (threadIdx.x == 0) { s_nf = 0; s_oddnz = 0; }
    __syncthreads();
    int nf = 0;
    for (int i = threadIdx.x; i < 16384; i += blockDim.x) {
        const unsigned short u = hraw[i];
        if (((u >> 7) & 0xFF) == 0xFF) nf++;
    }
    int onz = 0;
    for (int i = threadIdx.x; i < 512; i += blockDim.x) {
        if (eiraw[2*i + 1] != 0) onz++;
    }
    if (nf)  atomicAdd(&s_nf, nf);
    if (onz) atomicAdd(&s_oddnz, onz);
    __syncthreads();
    if (threadIdx.x == 0) {
        flags[0] = (s_nf > 0) ? 1 : 0;
        flags[1] = (s_oddnz == 0) ? 1 : 0;
    }
}

// ---------------------------------------------------------------------------
// CSR build: dst histogram (raw ei) -> scan -> scatter+geometry (fused)
// ---------------------------------------------------------------------------
__global__ void histd_kernel(const void* __restrict__ ei, int* __restrict__ cnt,
                             const int* __restrict__ flags, int Ee)
{
    const int e = blockIdx.x*blockDim.x + threadIdx.x;
    if (e < Ee) atomicAdd(&cnt[eidx(ei, Ee + e, flags[1] != 0)], 1);
}

__global__ void scanA_kernel(const int* __restrict__ cnt, int* __restrict__ bsum, int Nn)
{
    __shared__ int s[512];
    const int gi = blockIdx.x*512 + threadIdx.x;
    s[threadIdx.x] = (gi < Nn) ? cnt[gi] : 0;
    __syncthreads();
    for (int off = 256; off > 0; off >>= 1) {
        if (threadIdx.x < off) s[threadIdx.x] += s[threadIdx.x + off];
        __syncthreads();
    }
    if (threadIdx.x == 0) bsum[blockIdx.x] = s[0];
}

__global__ void scanB_kernel(int* __restrict__ bsum, int* __restrict__ base, int nCh)
{
    if (threadIdx.x == 0) {
        int acc = 0;
        for (int b = 0; b < nCh; ++b) { base[b] = acc; acc += bsum[b]; }
    }
}

__global__ void scanC_kernel(const int* __restrict__ cnt, const int* __restrict__ base,
                             int* __restrict__ off, int* __restrict__ cursor, int Nn)
{
    __shared__ int s[512];
    const int i  = threadIdx.x;
    const int gi = blockIdx.x*512 + i;
    const int v  = (gi < Nn) ? cnt[gi] : 0;
    s[i] = v;
    __syncthreads();
    for (int o = 1; o < 512; o <<= 1) {
        const int t = (i >= o) ? s[i - o] : 0;
        __syncthreads();
        s[i] += t;
        __syncthreads();
    }
    const int excl = s[i] - v;
    if (gi <= Nn) {
        const int val = base[blockIdx.x] + excl;
        off[gi] = val;
        if (gi < Nn) cursor[gi] = val;
    }
}

// ---------------------------------------------------------------------------
// Fused scatgeo + proj: blocks [0, projBlocks) run the persistent proj GEMM
// (tiles stride projBlocks); blocks [projBlocks, grid) grid-stride scatgeo.
// Both are independent and latency-bound -> co-residency gives max not sum.
// ---------------------------------------------------------------------------
__global__ __launch_bounds__(512, 2)
void scatgeo_proj_kernel(const void* __restrict__ ei, int* __restrict__ cursor,
                         int* __restrict__ srcs, int* __restrict__ dsts,
                         float4* __restrict__ rel4, const void* __restrict__ x,
                         const void* __restrict__ h, const void* __restrict__ We1,
                         const void* __restrict__ be1, const int* __restrict__ flags,
                         __bf16* __restrict__ PB, int Nn, int Ee, int projBlocks)
{
    __shared__ __bf16 s_h[32*136];
    const bool f32 = flags[0] != 0;
    const int tid  = threadIdx.x;

    if ((int)blockIdx.x >= projBlocks) {
        // ---------------- scatgeo path (grid-stride) ----------------
        const bool i64 = flags[1] != 0;
        const int nb = gridDim.x - projBlocks;
        for (int e = ((int)blockIdx.x - projBlocks)*512 + tid; e < Ee; e += nb*512) {
            const int s = eidx(ei, e, i64);
            const int d = eidx(ei, Ee + e, i64);
            const int p = atomicAdd(&cursor[d], 1);
            srcs[p] = s;
            dsts[p] = d;
            float r[3];
            #pragma unroll
            for (int c = 0; c < 3; ++c)
                r[c] = wload(x, s*3 + c, f32) - wload(x, d*3 + c, f32);
            float4 o; o.x = r[0]; o.y = r[1]; o.z = r[2];
            o.w = r[0]*r[0] + r[1]*r[1] + r[2]*r[2];
            rel4[p] = o;
        }
        return;
    }

    // ---------------- proj path (persistent, stride projBlocks) ----------------
    const int wv   = tid >> 6;
    const int lane = tid & 63;
    const int quad = lane >> 4;
    const int l15  = lane & 15;

    bf8_t bW[4][2];
    float bias[2];
    #pragma unroll
    for (int t = 0; t < 2; ++t) {
        const int n    = wv*32 + t*16 + l15;
        const int rb   = (n < 128) ? 0 : 128;
        const int col  = n & 127;
        #pragma unroll
        for (int kc = 0; kc < 4; ++kc) {
            bf8_t v;
            #pragma unroll
            for (int j = 0; j < 8; ++j)
                v[j] = (__bf16)wload(We1, (rb + kc*32 + quad*8 + j)*H + col, f32);
            bW[kc][t] = v;
        }
        bias[t] = (n < 128) ? 0.f : wload(be1, col, f32);
    }

    const int tiles = (Nn + 31) >> 5;
    for (int tile = blockIdx.x; tile < tiles; tile += projBlocks) {
        const int nb2 = tile << 5;
        __syncthreads();
        {
            const int m = tid >> 4, c = tid & 15;
            int node = nb2 + m; if (node >= Nn) node = Nn - 1;
            *(bf8_t*)&s_h[m*136 + c*8] = hload8(h, (size_t)node*H + c*8, f32);
        }
        __syncthreads();

        f4_t acc[2][2];
        #pragma unroll
        for (int mm = 0; mm < 2; ++mm)
            #pragma unroll
            for (int t = 0; t < 2; ++t) acc[mm][t] = (f4_t){0.f,0.f,0.f,0.f};
        #pragma unroll
        for (int kc = 0; kc < 4; ++kc) {
            #pragma unroll
            for (int mm = 0; mm < 2; ++mm) {
                const bf8_t a = *(const bf8_t*)&s_h[(mm*16 + l15)*136 + quad*8 + kc*32];
                acc[mm][0] = MFMA16(a, bW[kc][0], acc[mm][0]);
                acc[mm][1] = MFMA16(a, bW[kc][1], acc[mm][1]);
            }
        }
        #pragma unroll
        for (int mm = 0; mm < 2; ++mm)
            #pragma unroll
            for (int i = 0; i < 4; ++i) {
                const int row = nb2 + mm*16 + quad*4 + i;
                if (row < Nn) {
                    #pragma unroll
                    for (int t = 0; t < 2; ++t)
                        PB[(size_t)row*256 + wv*32 + t*16 + l15] =
                            (__bf16)(acc[mm][t][i] + bias[t]);
                }
            }
    }
}

// ---------------------------------------------------------------------------
// Edge kernel (R6 structure, 2 barriers/tile): the merge+coord phase for tile
// t-1 is DEFERRED into the bar1->bar2 window of tile t (double-buffered
// s_pre/s_suf/s_wh/s_cw), where it overlaps the all-wave L2 MFMA instead of
// sitting behind a third barrier. Exactly-once semantics unchanged: dsts
// shared across tiles are atomic in both tiles; interior stores never alias.
// ---------------------------------------------------------------------------
__global__ __launch_bounds__(512, 2)
void egnn_edge_pipe_kernel(const __bf16* __restrict__ PB,
                           const int* __restrict__ srcs, const int* __restrict__ dsts,
                           const float4* __restrict__ rel4,
                           const void* __restrict__ We1,  // row 256 only (w1d)
                           const void* __restrict__ We2, const void* __restrict__ be2,
                           const void* __restrict__ Wc1, const void* __restrict__ bc1,
                           const void* __restrict__ Wc2, const int* __restrict__ flags,
                           float* __restrict__ msg, float* __restrict__ coord,
                           int Ee)
{
    const bool f32 = flags[0] != 0;
    const int tid  = threadIdx.x;
    const int wv   = tid >> 6;
    const int lane = tid & 63;
    const int quad = lane >> 4;
    const int l15  = lane & 15;
    const int mg   = wv >> 2;
    const int ng   = wv & 3;

    bf8_t bW2[4][2], bWc[4][2];
    float be2v[2], bc1v[2], wc2v[2];
    #pragma unroll
    for (int t = 0; t < 2; ++t) {
        const int n = ng*32 + t*16 + l15;
        #pragma unroll
        for (int kc = 0; kc < 4; ++kc) {
            bf8_t v, u;
            #pragma unroll
            for (int j = 0; j < 8; ++j) {
                v[j] = (__bf16)wload(We2, (kc*32 + quad*8 + j)*H + n, f32);
                u[j] = (__bf16)wload(Wc1, (kc*32 + quad*8 + j)*H + n, f32);
            }
            bW2[kc][t] = v;
            bWc[kc][t] = u;
        }
        be2v[t] = wload(be2, n, f32);
        bc1v[t] = wload(bc1, n, f32);
        wc2v[t] = wload(Wc2, n, f32);
    }

    const int em = tid >> 3;          // edge row 0..63
    const int ch = tid & 7;           // 2 column-chunks per thread
    float w1dA[8], w1dB[8];
    #pragma unroll
    for (int j = 0; j < 8; ++j) {
        w1dA[j] = wload(We1, 256*H + ch*8 + j, f32);
        w1dB[j] = wload(We1, 256*H + (ch+8)*8 + j, f32);
    }

    __shared__ __bf16 s_m1[64*136];
    __shared__ __bf16 s_m2[64*136];
    __shared__ float  s_cw[2][4*64];     // [buf][ng][edge]
    __shared__ int    s_dst[2][64];
    __shared__ float4 s_rl[2][64];
    __shared__ float  s_pre[2][8][128];  // leading-run sum per 8-row group
    __shared__ float  s_suf[2][8][128];  // trailing-run sum per 8-row group
    __shared__ int    s_wh[2][8];        // group is a single run

    const int tiles = (Ee + 63) >> 6;
    const float* rw = (const float*)rel4;

    bf8_t rA0, rA1, rB0, rB1;
    float d2cur, d2nxt;
    int   s_n, d_n, d_c;
    float4 r4c, r4n;
    {
        int e0 = blockIdx.x*64 + em; if (e0 >= Ee) e0 = Ee - 1;
        const int sc = srcs[e0], dc = dsts[e0];
        d_c = dc;
        d2cur = rw[(size_t)e0*4 + 3];
        if (ch == 0) r4c = rel4[e0];
        rA0 = *(const bf8_t*)(PB + (size_t)sc*256 + ch*8);
        rA1 = *(const bf8_t*)(PB + (size_t)sc*256 + (ch+8)*8);
        rB0 = *(const bf8_t*)(PB + (size_t)dc*256 + 128 + ch*8);
        rB1 = *(const bf8_t*)(PB + (size_t)dc*256 + 128 + (ch+8)*8);
        const int t1 = blockIdx.x + gridDim.x;
        const int tt = (t1 < tiles) ? t1 : blockIdx.x;
        int e1 = tt*64 + em; if (e1 >= Ee) e1 = Ee - 1;
        s_n = srcs[e1]; d_n = dsts[e1]; d2nxt = rw[(size_t)e1*4 + 3];
        if (ch == 0) r4n = rel4[e1];
    }

    int li = 0;
    for (int t = blockIdx.x; t < tiles; t += gridDim.x, ++li) {
        const int sb = li & 1;
        const int pb = sb ^ 1;
        // ---- stage layer-1 output + dst/rel staging ----
        {
            bf8_t o0, o1;
            #pragma unroll
            for (int j = 0; j < 8; ++j) {
                const float f0 = (float)rA0[j] + (float)rB0[j] + d2cur*w1dA[j];
                const float f1 = (float)rA1[j] + (float)rB1[j] + d2cur*w1dB[j];
                o0[j] = (__bf16)silu_f(f0);
                o1[j] = (__bf16)silu_f(f1);
            }
            *(bf8_t*)&s_m1[em*136 + ch*8]       = o0;
            *(bf8_t*)&s_m1[em*136 + (ch+8)*8]   = o1;
            if (ch == 0) { s_dst[sb][em] = d_c; s_rl[sb][em] = r4c; }
        }
        // ---- prefetch next tile ----
        {
            const int sc = s_n, dc2 = d_n;
            rA0 = *(const bf8_t*)(PB + (size_t)sc*256 + ch*8);
            rA1 = *(const bf8_t*)(PB + (size_t)sc*256 + (ch+8)*8);
            rB0 = *(const bf8_t*)(PB + (size_t)dc2*256 + 128 + ch*8);
            rB1 = *(const bf8_t*)(PB + (size_t)dc2*256 + 128 + (ch+8)*8);
            d_c = d_n; d2cur = d2nxt;
            if (ch == 0) r4c = r4n;
            const int t2 = t + 2*gridDim.x;
            const int tt = (t2 < tiles) ? t2 : t;
            int e2 = tt*64 + em; if (e2 >= Ee) e2 = Ee - 1;
            s_n = srcs[e2]; d_n = dsts[e2]; d2nxt = rw[(size_t)e2*4 + 3];
            if (ch == 0) r4n = rel4[e2];
        }
        bar_lds();

        // ---- DEFERRED: msg merge + coord scan for tile t-1 (buffers pb) ----
        // Runs in the bar1->bar2 window, overlapping the all-wave L2 MFMA.
        if (li > 0) {
            if (tid >= 128 && tid < 256) {
                const int c = tid - 128;
                int   curd2 = __builtin_amdgcn_readfirstlane(s_dst[pb][0]);
                float cur   = 0.f;
                int   first = 1;
                #pragma unroll
                for (int gg = 0; gg < 8; ++gg) {
                    const int F  = __builtin_amdgcn_readfirstlane(s_dst[pb][gg*8]);
                    const int L  = __builtin_amdgcn_readfirstlane(s_dst[pb][gg*8 + 7]);
                    const int wh = __builtin_amdgcn_readfirstlane(s_wh[pb][gg]);
                    const float preg = s_pre[pb][gg][c];
                    const float sufg = s_suf[pb][gg][c];
                    if (F != curd2) {
                        if (first) atomicAdd(&msg[(size_t)curd2*H + c], cur);
                        else       msg[(size_t)curd2*H + c] = cur;
                        first = 0; curd2 = F; cur = 0.f;
                    }
                    if (wh) {
                        cur += sufg;
                    } else {
                        cur += preg;
                        if (first) atomicAdd(&msg[(size_t)curd2*H + c], cur);
                        else       msg[(size_t)curd2*H + c] = cur;
                        first = 0; curd2 = L; cur = sufg;
                    }
                }
                atomicAdd(&msg[(size_t)curd2*H + c], cur);  // last run: boundary
            }
            if (tid < 64) {
                const int e = tid;
                const float cwv = s_cw[pb][e] + s_cw[pb][64 + e] +
                                  s_cw[pb][128 + e] + s_cw[pb][192 + e];
                const float4 r = s_rl[pb][e];
                const int d = s_dst[pb][e];
                float vx = r.x*cwv, vy = r.y*cwv, vz = r.z*cwv;
                int   cn = 1;
                #pragma unroll
                for (int k = 1; k < 64; k <<= 1) {
                    const int   dk = __shfl_up(d,  k, 64);
                    const float xk = __shfl_up(vx, k, 64);
                    const float yk = __shfl_up(vy, k, 64);
                    const float zk = __shfl_up(vz, k, 64);
                    const int   ck = __shfl_up(cn, k, 64);
                    if (e >= k && dk == d) { vx += xk; vy += yk; vz += zk; cn += ck; }
                }
                const int dnx = __shfl_down(d, 1, 64);
                const bool runend = (e == 63) || (dnx != d);
                if (runend) {
                    const int rs = e - cn + 1;
                    if (rs == 0 || e == 63) {
                        atomicAdd(&coord[(size_t)d*3 + 0], vx);
                        atomicAdd(&coord[(size_t)d*3 + 1], vy);
                        atomicAdd(&coord[(size_t)d*3 + 2], vz);
                    } else {
                        coord[(size_t)d*3 + 0] = vx;
                        coord[(size_t)d*3 + 1] = vy;
                        coord[(size_t)d*3 + 2] = vz;
                    }
                }
            }
        }

        // ---- layer 2: m2 = silu(m1 @ We2 + be2) ----
        {
            f4_t a2[2][2];
            #pragma unroll
            for (int mm = 0; mm < 2; ++mm)
                #pragma unroll
                for (int h2 = 0; h2 < 2; ++h2) a2[mm][h2] = (f4_t){0.f,0.f,0.f,0.f};
            #pragma unroll
            for (int kc = 0; kc < 4; ++kc) {
                #pragma unroll
                for (int mm = 0; mm < 2; ++mm) {
                    const bf8_t a = *(const bf8_t*)&s_m1[(mg*32 + mm*16 + l15)*136 + quad*8 + kc*32];
                    a2[mm][0] = MFMA16(a, bW2[kc][0], a2[mm][0]);
                    a2[mm][1] = MFMA16(a, bW2[kc][1], a2[mm][1]);
                }
            }
            #pragma unroll
            for (int mm = 0; mm < 2; ++mm)
                #pragma unroll
                for (int i = 0; i < 4; ++i) {
                    const int m = mg*32 + mm*16 + quad*4 + i;
                    s_m2[m*136 + ng*32 + l15]      = (__bf16)silu_f(a2[mm][0][i] + be2v[0]);
                    s_m2[m*136 + ng*32 + 16 + l15] = (__bf16)silu_f(a2[mm][1][i] + be2v[1]);
                }
        }
        bar_lds();

        // ---- layer 3: coord head partials -> s_cw[sb] ----
        {
            f4_t a3[2][2];
            #pragma unroll
            for (int mm = 0; mm < 2; ++mm)
                #pragma unroll
                for (int h2 = 0; h2 < 2; ++h2) a3[mm][h2] = (f4_t){0.f,0.f,0.f,0.f};
            #pragma unroll
            for (int kc = 0; kc < 4; ++kc) {
                #pragma unroll
                for (int mm = 0; mm < 2; ++mm) {
                    const bf8_t a = *(const bf8_t*)&s_m2[(mg*32 + mm*16 + l15)*136 + quad*8 + kc*32];
                    a3[mm][0] = MFMA16(a, bWc[kc][0], a3[mm][0]);
                    a3[mm][1] = MFMA16(a, bWc[kc][1], a3[mm][1]);
                }
            }
            float p[2][4];
            #pragma unroll
            for (int mm = 0; mm < 2; ++mm)
                #pragma unroll
                for (int i = 0; i < 4; ++i) {
                    const float v0 = silu_f(a3[mm][0][i] + bc1v[0]);
                    const float v1 = silu_f(a3[mm][1][i] + bc1v[1]);
                    p[mm][i] = v0*wc2v[0] + v1*wc2v[1];
                }
            #pragma unroll
            for (int off = 1; off < 16; off <<= 1)
                #pragma unroll
                for (int mm = 0; mm < 2; ++mm)
                    #pragma unroll
                    for (int i = 0; i < 4; ++i) p[mm][i] += __shfl_xor(p[mm][i], off, 64);
            if (l15 == 0) {
                #pragma unroll
                for (int mm = 0; mm < 2; ++mm)
                    #pragma unroll
                    for (int i = 0; i < 4; ++i)
                        s_cw[sb][ng*64 + (mg*32 + mm*16 + quad*4 + i)] = p[mm][i];
            }
        }

        // ---- msg per-group scan: wave wv owns rows wv*8..wv*8+7, all 128
        //      cols (2 adjacent cols per lane). Writes s_pre/s_suf/s_wh[sb];
        //      interior runs stored directly (exactly-once).
        {
            const int rbase = wv << 3;
            const int c0    = lane << 1;
            int   curd = __builtin_amdgcn_readfirstlane(s_dst[sb][rbase]);
            float ax = 0.f, ay = 0.f;
            float px = 0.f, py = 0.f;
            int   predone = 0;
            #pragma unroll
            for (int i = 0; i < 8; ++i) {
                const int d = __builtin_amdgcn_readfirstlane(s_dst[sb][rbase + i]);
                const bf2_t v = *(const bf2_t*)&s_m2[(rbase + i)*136 + c0];
                const float vx = (float)v[0], vy = (float)v[1];
                if (d != curd) {
                    if (!predone) { px = ax; py = ay; predone = 1; }
                    else {
                        float2 st; st.x = ax; st.y = ay;
                        *(float2*)&msg[(size_t)curd*H + c0] = st;   // interior run
                    }
                    curd = d; ax = vx; ay = vy;
                } else { ax += vx; ay += vy; }
            }
            s_pre[sb][wv][c0]   = px;  s_pre[sb][wv][c0+1] = py;
            s_suf[sb][wv][c0]   = ax;  s_suf[sb][wv][c0+1] = ay;
            if (lane == 0) s_wh[sb][wv] = !predone;
        }
        // no 3rd barrier: merge+coord for this tile run after next bar1
    }

    // ---- epilogue: flush merge + coord for the final tile ----
    if (li > 0) {
        bar_lds();
        const int pb = (li - 1) & 1;
        if (tid >= 128 && tid < 256) {
            const int c = tid - 128;
            int   curd2 = __builtin_amdgcn_readfirstlane(s_dst[pb][0]);
            float cur   = 0.f;
            int   first = 1;
            #pragma unroll
            for (int gg = 0; gg < 8; ++gg) {
                const int F  = __builtin_amdgcn_readfirstlane(s_dst[pb][gg*8]);
                const int L  = __builtin_amdgcn_readfirstlane(s_dst[pb][gg*8 + 7]);
                const int wh = __builtin_amdgcn_readfirstlane(s_wh[pb][gg]);
                const float preg = s_pre[pb][gg][c];
                const float sufg = s_suf[pb][gg][c];
                if (F != curd2) {
                    if (first) atomicAdd(&msg[(size_t)curd2*H + c], cur);
                    else       msg[(size_t)curd2*H + c] = cur;
                    first = 0; curd2 = F; cur = 0.f;
                }
                if (wh) {
                    cur += sufg;
                } else {
                    cur += preg;
                    if (first) atomicAdd(&msg[(size_t)curd2*H + c], cur);
                    else       msg[(size_t)curd2*H + c] = cur;
                    first = 0; curd2 = L; cur = sufg;
                }
            }
            atomicAdd(&msg[(size_t)curd2*H + c], cur);
        }
        if (tid < 64) {
            const int e = tid;
            const float cwv = s_cw[pb][e] + s_cw[pb][64 + e] +
                              s_cw[pb][128 + e] + s_cw[pb][192 + e];
            const float4 r = s_rl[pb][e];
            const int d = s_dst[pb][e];
            float vx = r.x*cwv, vy = r.y*cwv, vz = r.z*cwv;
            int   cn = 1;
            #pragma unroll
            for (int k = 1; k < 64; k <<= 1) {
                const int   dk = __shfl_up(d,  k, 64);
                const float xk = __shfl_up(vx, k, 64);
                const float yk = __shfl_up(vy, k, 64);
                const float zk = __shfl_up(vz, k, 64);
                const int   ck = __shfl_up(cn, k, 64);
                if (e >= k && dk == d) { vx += xk; vy += yk; vz += zk; cn += ck; }
            }
            const int dnx = __shfl_down(d, 1, 64);
            const bool runend = (e == 63) || (dnx != d);
            if (runend) {
                const int rs = e - cn + 1;
                if (rs == 0 || e == 63) {
                    atomicAdd(&coord[(size_t)d*3 + 0], vx);
                    atomicAdd(&coord[(size_t)d*3 + 1], vy);
                    atomicAdd(&coord[(size_t)d*3 + 2], vz);
                } else {
                    coord[(size_t)d*3 + 0] = vx;
                    coord[(size_t)d*3 + 1] = vy;
                    coord[(size_t)d*3 + 2] = vz;
                }
            }
        }
    }
}

// ---------------------------------------------------------------------------
// Node kernel: h_out = h + silu([h | msg] @ Wn1 + bn1) @ Wn2 + bn2
// msg is f32. Optionally also emits x_out = x + coord (do_x).
// ---------------------------------------------------------------------------
__global__ __launch_bounds__(512, 2)
void egnn_node_kernel(const void* __restrict__ h, const float* __restrict__ msg,
                      const void* __restrict__ Wn1, const void* __restrict__ bn1,
                      const void* __restrict__ Wn2, const void* __restrict__ bn2,
                      const int* __restrict__ flags, void* __restrict__ h_out,
                      const void* __restrict__ x, const float* __restrict__ coord,
                      size_t obase, int do_x, int Nn)
{
    const bool f32 = flags[0] != 0;
    const int tid  = threadIdx.x;
    const int wv   = tid >> 6;
    const int lane = tid & 63;
    const int quad = lane >> 4;
    const int l15  = lane & 15;
    const int mg   = wv >> 2;
    const int ng   = wv & 3;

    bf8_t bW1[8][2];
    bf8_t bW2[4][2];
    float b1v[2], b2v[2];
    #pragma unroll
    for (int t = 0; t < 2; ++t) {
        const int n = ng*32 + t*16 + l15;
        #pragma unroll
        for (int kc = 0; kc < 8; ++kc) {
            bf8_t v;
            #pragma unroll
            for (int j = 0; j < 8; ++j) v[j] = (__bf16)wload(Wn1, (kc*32 + quad*8 + j)*H + n, f32);
            bW1[kc][t] = v;
        }
        #pragma unroll
        for (int kc = 0; kc < 4; ++kc) {
            bf8_t v;
            #pragma unroll
            for (int j = 0; j < 8; ++j) v[j] = (__bf16)wload(Wn2, (kc*32 + quad*8 + j)*H + n, f32);
            bW2[kc][t] = v;
        }
        b1v[t] = wload(bn1, n, f32);
        b2v[t] = wload(bn2, n, f32);
    }

    __shared__ __bf16 s_in[32*264];
    __shared__ __bf16 s_t1[32*136];

    const int tiles = (Nn + 31) >> 5;
    for (int tile = blockIdx.x; tile < tiles; tile += gridDim.x) {
        const int nb = tile << 5;
        __syncthreads();
        #pragma unroll
        for (int r = 0; r < 2; ++r) {
            const int idx = tid + r*512;
            const int m = idx >> 5, c = idx & 31;
            int node = nb + m;
            if (node >= Nn) node = Nn - 1;
            if (c < 16) {
                *(bf8_t*)&s_in[m*264 + c*8] = hload8(h, (size_t)node*H + c*8, f32);
            } else {
                const float4* mp = (const float4*)(msg + (size_t)node*H + (c - 16)*8);
                const float4 v0 = mp[0], v1 = mp[1];
                __bf16* d = &s_in[m*264 + c*8];
                d[0] = (__bf16)v0.x; d[1] = (__bf16)v0.y; d[2] = (__bf16)v0.z; d[3] = (__bf16)v0.w;
                d[4] = (__bf16)v1.x; d[5] = (__bf16)v1.y; d[6] = (__bf16)v1.z; d[7] = (__bf16)v1.w;
            }
        }
        // x_out epilogue (independent of LDS)
        if (do_x && tid < 96) {
            const int m = tid / 3, c = tid - m*3;
            const int node = nb + m;
            if (node < Nn) {
                const float xv = wload(x, node*3 + c, f32);
                const float o = xv + coord[(size_t)node*3 + c];
                if (f32) ((float*)h_out)[obase + (size_t)node*3 + c] = o;
                else     ((__bf16*)h_out)[obase + (size_t)node*3 + c] = (__bf16)o;
            }
        }
        __syncthreads();

        {
            f4_t a0 = {0.f,0.f,0.f,0.f}, a1 = {0.f,0.f,0.f,0.f};
            const int abase = (mg*16 + l15)*264 + quad*8;
            #pragma unroll
            for (int kc = 0; kc < 8; ++kc) {
                const bf8_t a = *(const bf8_t*)&s_in[abase + kc*32];
                a0 = MFMA16(a, bW1[kc][0], a0);
                a1 = MFMA16(a, bW1[kc][1], a1);
            }
            #pragma unroll
            for (int i = 0; i < 4; ++i) {
                const int m = mg*16 + quad*4 + i;
                s_t1[m*136 + ng*32 + l15]      = (__bf16)silu_f(a0[i] + b1v[0]);
                s_t1[m*136 + ng*32 + 16 + l15] = (__bf16)silu_f(a1[i] + b1v[1]);
            }
        }
        __syncthreads();

        {
            f4_t a0 = {0.f,0.f,0.f,0.f}, a1 = {0.f,0.f,0.f,0.f};
            const int abase = (mg*16 + l15)*136 + quad*8;
            #pragma unroll
            for (int kc = 0; kc < 4; ++kc) {
                const bf8_t a = *(const bf8_t*)&s_t1[abase + kc*32];
                a0 = MFMA16(a, bW2[kc][0], a0);
                a1 = MFMA16(a, bW2[kc][1], a1);
            }
            #pragma unroll
            for (int i = 0; i < 4; ++i) {
                const int node = nb + mg*16 + quad*4 + i;
                if (node < Nn) {
                    const int n0 = ng*32 + l15, n1 = n0 + 16;
                    const size_t i0 = (size_t)node*H + n0, i1 = (size_t)node*H + n1;
                    const float h0 = f32 ? ((const float*)h)[i0] : (float)((const __bf16*)h)[i0];
                    const float h1 = f32 ? ((const float*)h)[i1] : (float)((const __bf16*)h)[i1];
                    const float o0 = a0[i] + b2v[0] + h0;
                    const float o1 = a1[i] + b2v[1] + h1;
                    if (f32) {
                        ((float*)h_out)[i0] = o0;
                        ((float*)h_out)[i1] = o1;
                    } else {
                        ((__bf16*)h_out)[i0] = (__bf16)o0;
                        ((__bf16*)h_out)[i1] = (__bf16)o1;
                    }
                }
            }
        }
    }
}

// ---------------------------------------------------------------------------
// Fallback (R2 atomic path)
// ---------------------------------------------------------------------------
__global__ void cvt_ei_kernel(const void* __restrict__ src, int* __restrict__ dst,
                              int n, const int* __restrict__ flags)
{
    const int i = blockIdx.x*blockDim.x + threadIdx.x;
    if (i >= n) return;
    dst[i] = flags[1] ? (int)((const long long*)src)[i] : ((const int*)src)[i];
}

__global__ __launch_bounds__(512, 2)
void egnn_edge_kernel(const void* __restrict__ h, const void* __restrict__ x,
                      const int* __restrict__ ei,
                      const void* __restrict__ We1, const void* __restrict__ be1,
                      const void* __restrict__ We2, const void* __restrict__ be2,
                      const void* __restrict__ Wc1, const void* __restrict__ bc1,
                      const void* __restrict__ Wc2, const int* __restrict__ flags,
                      float* __restrict__ msg_agg, float* __restrict__ coord_agg,
                      int Nn, int Ee)
{
    const bool f32 = flags[0] != 0;
    const int tid  = threadIdx.x;
    const int wv   = tid >> 6;
    const int lane = tid & 63;
    const int quad = lane >> 4;
    const int l15  = lane & 15;
    const int mg   = wv >> 2;
    const int ng   = wv & 3;

    bf8_t bW1[8][2];
    bf8_t bW2[4][2];
    bf8_t bWc[4][2];
    float be1v[2], be2v[2], bc1v[2], w1dv[2], wc2v[2];
    #pragma unroll
    for (int t = 0; t < 2; ++t) {
        const int n = ng*32 + t*16 + l15;
        #pragma unroll
        for (int kc = 0; kc < 8; ++kc) {
            bf8_t v;
            #pragma unroll
            for (int j = 0; j < 8; ++j) v[j] = (__bf16)wload(We1, (kc*32 + quad*8 + j)*H + n, f32);
            bW1[kc][t] = v;
        }
        #pragma unroll
        for (int kc = 0; kc < 4; ++kc) {
            bf8_t v, u;
            #pragma unroll
            for (int j = 0; j < 8; ++j) {
                v[j] = (__bf16)wload(We2, (kc*32 + quad*8 + j)*H + n, f32);
                u[j] = (__bf16)wload(Wc1, (kc*32 + quad*8 + j)*H + n, f32);
            }
            bW2[kc][t] = v;
            bWc[kc][t] = u;
        }
        be1v[t] = wload(be1, n, f32);
        be2v[t] = wload(be2, n, f32);
        bc1v[t] = wload(bc1, n, f32);
        w1dv[t] = wload(We1, 256*H + n, f32);
        wc2v[t] = wload(Wc2, n, f32);
    }

    __shared__ __bf16 s_in[32*264];
    __shared__ __bf16 s_m1[32*136];
    __shared__ __bf16 s_m2[32*136];
    __shared__ float  s_rel[32*3];
    __shared__ float  s_dist[32];
    __shared__ int    s_dstv[32];
    __shared__ float  s_cw[32*4];

    const int tiles = Ee >> 5;
    for (int tile = blockIdx.x; tile < tiles; tile += gridDim.x) {
        const int ebase = tile << 5;
        __syncthreads();

        if (tid < 32) {
            const int e  = ebase + tid;
            const int sn = ei[e];
            const int dn = ei[Ee + e];
            s_dstv[tid] = dn;
            float d2 = 0.f;
            #pragma unroll
            for (int c = 0; c < 3; ++c) {
                float r;
                if (f32) r = ((const float*)x)[sn*3 + c] - ((const float*)x)[dn*3 + c];
                else     r = (float)((const __bf16*)x)[sn*3 + c] - (float)((const __bf16*)x)[dn*3 + c];
                s_rel[tid*3 + c] = r;
                d2 += r*r;
            }
            s_dist[tid] = d2;
        }
        #pragma unroll
        for (int r = 0; r < 2; ++r) {
            const int idx = tid + r*512;
            const int m = idx >> 5, c = idx & 31;
            const int e = ebase + m;
            const int node = (c < 16) ? ei[e] : ei[Ee + e];
            *(bf8_t*)&s_in[m*264 + c*8] = hload8(h, (size_t)node*H + (c & 15)*8, f32);
        }
        __syncthreads();

        {
            f4_t a0 = {0.f,0.f,0.f,0.f}, a1 = {0.f,0.f,0.f,0.f};
            const int abase = (mg*16 + l15)*264 + quad*8;
            #pragma unroll
            for (int kc = 0; kc < 8; ++kc) {
                const bf8_t a = *(const bf8_t*)&s_in[abase + kc*32];
                a0 = MFMA16(a, bW1[kc][0], a0);
                a1 = MFMA16(a, bW1[kc][1], a1);
            }
            #pragma unroll
            for (int i = 0; i < 4; ++i) {
                const int m = mg*16 + quad*4 + i;
                const float d2 = s_dist[m];
                s_m1[m*136 + ng*32 + l15]      = (__bf16)silu_f(a0[i] + d2*w1dv[0] + be1v[0]);
                s_m1[m*136 + ng*32 + 16 + l15] = (__bf16)silu_f(a1[i] + d2*w1dv[1] + be1v[1]);
            }
        }
        __syncthreads();

        {
            f4_t a0 = {0.f,0.f,0.f,0.f}, a1 = {0.f,0.f,0.f,0.f};
            const int abase = (mg*16 + l15)*136 + quad*8;
            #pragma unroll
            for (int kc = 0; kc < 4; ++kc) {
                const bf8_t a = *(const bf8_t*)&s_m1[abase + kc*32];
                a0 = MFMA16(a, bW2[kc][0], a0);
                a1 = MFMA16(a, bW2[kc][1], a1);
            }
            #pragma unroll
            for (int i = 0; i < 4; ++i) {
                const int m = mg*16 + quad*4 + i;
                const float v0 = silu_f(a0[i] + be2v[0]);
                const float v1 = silu_f(a1[i] + be2v[1]);
                s_m2[m*136 + ng*32 + l15]      = (__bf16)v0;
                s_m2[m*136 + ng*32 + 16 + l15] = (__bf16)v1;
                const size_t db = (size_t)s_dstv[m]*H + ng*32 + l15;
                atomicAdd(&msg_agg[db],      v0);
                atomicAdd(&msg_agg[db + 16], v1);
            }
        }
        __syncthreads();

        {
            f4_t a0 = {0.f,0.f,0.f,0.f}, a1 = {0.f,0.f,0.f,0.f};
            const int abase = (mg*16 + l15)*136 + quad*8;
            #pragma unroll
            for (int kc = 0; kc < 4; ++kc) {
                const bf8_t a = *(const bf8_t*)&s_m2[abase + kc*32];
                a0 = MFMA16(a, bWc[kc][0], a0);
                a1 = MFMA16(a, bWc[kc][1], a1);
            }
            float p[4];
            #pragma unroll
            for (int i = 0; i < 4; ++i) {
                const float v0 = silu_f(a0[i] + bc1v[0]);
                const float v1 = silu_f(a1[i] + bc1v[1]);
                p[i] = v0*wc2v[0] + v1*wc2v[1];
            }
            #pragma unroll
            for (int off = 1; off < 16; off <<= 1) {
                #pragma unroll
                for (int i = 0; i < 4; ++i) p[i] += __shfl_xor(p[i], off, 64);
            }
            if (l15 == 0) {
                #pragma unroll
                for (int i = 0; i < 4; ++i)
                    s_cw[(mg*16 + quad*4 + i)*4 + ng] = p[i];
            }
        }
        __syncthreads();

        if (tid < 96) {
            const int m = tid / 3, c = tid - m*3;
            const float cw = s_cw[m*4 + 0] + s_cw[m*4 + 1] + s_cw[m*4 + 2] + s_cw[m*4 + 3];
            atomicAdd(&coord_agg[(size_t)s_dstv[m]*3 + c], s_rel[m*3 + c]*cw);
        }
    }
}

__global__ void egnn_x_kernel(const void* __restrict__ x, const float* __restrict__ coord_agg,
                              const int* __restrict__ flags, void* __restrict__ out,
                              size_t obase, int total)
{
    const bool f32 = flags[0] != 0;
    const int i = blockIdx.x*blockDim.x + threadIdx.x;
    if (i >= total) return;
    const float xv = f32 ? ((const float*)x)[i] : (float)((const __bf16*)x)[i];
    const float o = xv + coord_agg[i];
    if (f32) ((float*)out)[obase + i] = o;
    else     ((__bf16*)out)[obase + i] = (__bf16)o;
}

static inline size_t align256(size_t v) { return (v + 255) & ~(size_t)255; }

extern "C" void kernel_launch(void* const* d_in, const int* in_sizes, int n_in,
                              void* d_out, int out_size, void* d_ws, size_t ws_size,
                              hipStream_t stream)
{
    const void* h   = d_in[0];
    const void* x   = d_in[1];
    const void* ei0 = d_in[2];
    const void* We1 = d_in[3];
    const void* be1 = d_in[4];
    const void* We2 = d_in[5];
    const void* be2 = d_in[6];
    const void* Wc1 = d_in[7];
    const void* bc1 = d_in[8];
    const void* Wc2 = d_in[9];
    const void* Wn1 = d_in[10];
    const void* bn1 = d_in[11];
    const void* Wn2 = d_in[12];
    const void* bn2 = d_in[13];

    const int Nn = in_sizes[0] / H;   // 50000
    const int Ee = in_sizes[2] / 2;   // 640000

    char* ws = (char*)d_ws;
    size_t o = 0;
    // zero-init region: cnt | msg | coord (one memset)
    size_t o_cnt   = o; o = align256(o + (size_t)Nn*4);
    size_t o_msg   = o; o = align256(o + (size_t)Nn*H*4);      // msg_agg f32
    size_t o_coord = o; o = align256(o + (size_t)Nn*3*4);      // coord_agg f32
    const size_t zero_end = o;
    size_t o_srcs  = o; o = align256(o + (size_t)Ee*4);
    size_t o_dsts  = o; o = align256(o + (size_t)Ee*4);
    size_t o_rel   = o; o = align256(o + (size_t)Ee*16);       // rel4 (xyz, d2)
    size_t o_pb    = o; o = align256(o + (size_t)Nn*256*2);    // PB bf16 [N,256]
    size_t o_off   = o; o = align256(o + (size_t)(Nn+1)*4);
    size_t o_cur   = o; o = align256(o + (size_t)Nn*4);
    size_t o_bsum  = o; o = align256(o + 512*4);
    size_t o_base  = o; o = align256(o + 512*4);
    size_t o_flags = o; o = align256(o + 64);
    const size_t need_csr = o;

    const int nCh = (Nn + 1 + 511) / 512;

    if (ws_size >= need_csr) {
        int*    cnt     = (int*)   (ws + o_cnt);
        float*  msg     = (float*) (ws + o_msg);
        float*  coord   = (float*) (ws + o_coord);
        int*    srcs    = (int*)   (ws + o_srcs);
        int*    dsts    = (int*)   (ws + o_dsts);
        float4* rel4    = (float4*)(ws + o_rel);
        __bf16* PB      = (__bf16*)(ws + o_pb);
        int*    off     = (int*)   (ws + o_off);
        int*    cursor  = (int*)   (ws + o_cur);
        int*    bsum    = (int*)   (ws + o_bsum);
        int*    base    = (int*)   (ws + o_base);
        int*    flags   = (int*)   (ws + o_flags);

        detect_kernel<<<1, 256, 0, stream>>>((const unsigned short*)h, (const int*)ei0, flags);
        hipMemsetAsync(ws + o_cnt, 0, zero_end - o_cnt, stream);
        histd_kernel<<<(Ee + 511)/512, 512, 0, stream>>>(ei0, cnt, flags, Ee);
        scanA_kernel<<<nCh, 512, 0, stream>>>(cnt, bsum, Nn);
        scanB_kernel<<<1, 64, 0, stream>>>(bsum, base, nCh);
        scanC_kernel<<<nCh, 512, 0, stream>>>(cnt, base, off, cursor, Nn);

        // fused: 256 persistent proj blocks + 256 grid-stride scatgeo blocks,
        // all co-resident (2 blocks/CU) -> max instead of sum.
        scatgeo_proj_kernel<<<512, 512, 0, stream>>>(ei0, cursor, srcs, dsts, rel4,
                                                     x, h, We1, be1, flags, PB,
                                                     Nn, Ee, 256);

        // grid 512: ~20 tiles/block, 2 blocks/CU (R5-proven best config)
        egnn_edge_pipe_kernel<<<512, 512, 0, stream>>>(PB, srcs, dsts, rel4,
                                                       We1, We2, be2, Wc1, bc1, Wc2,
                                                       flags, msg, coord, Ee);

        egnn_node_kernel<<<1024, 512, 0, stream>>>(h, msg, Wn1, bn1, Wn2, bn2,
                                                   flags, d_out, x, coord,
                                                   (size_t)Nn*H, 1, Nn);
    } else {
        // fallback: proven R2 atomic path
        float* msg_agg   = (float*)ws;
        float* coord_agg = (float*)(ws + (size_t)Nn*H*4);
        int*   ei        = (int*)  (ws + (size_t)Nn*H*4 + (size_t)Nn*3*4);
        int*   flags     = (int*)  (ws + (size_t)Nn*H*4 + (size_t)Nn*3*4 + (size_t)2*Ee*4);

        detect_kernel<<<1, 256, 0, stream>>>((const unsigned short*)h, (const int*)ei0, flags);
        cvt_ei_kernel<<<(2*Ee + 255)/256, 256, 0, stream>>>(ei0, ei, 2*Ee, flags);
        hipMemsetAsync(msg_agg,   0, (size_t)Nn*H*4, stream);
        hipMemsetAsync(coord_agg, 0, (size_t)Nn*3*4, stream);
        egnn_edge_kernel<<<1024, 512, 0, stream>>>(h, x, ei, We1, be1, We2, be2,
                                                   Wc1, bc1, Wc2, flags,
                                                   msg_agg, coord_agg, Nn, Ee);
        egnn_node_kernel<<<512, 512, 0, stream>>>(h, msg_agg, Wn1, bn1, Wn2, bn2,
                                                  flags, d_out, x, coord_agg,
                                                  (size_t)Nn*H, 0, Nn);
        egnn_x_kernel<<<(Nn*3 + 255)/256, 256, 0, stream>>>(x, coord_agg, flags, d_out,
                                                            (size_t)Nn*H, Nn*3);
    }
}

// Round 7
// 601.758 us; speedup vs baseline: 2.2463x; 1.0730x over previous
//
#include <hip/hip_runtime.h>

#define H 128

typedef __bf16 bf8_t __attribute__((ext_vector_type(8)));
typedef __bf16 bf2_t __attribute__((ext_vector_type(2)));
typedef float  f4_t  __attribute__((ext_vector_type(4)));

#define MFMA16(a, b, c) __builtin_amdgcn_mfma_f32_16x16x32_bf16((a), (b), (c), 0, 0, 0)

__device__ __forceinline__ float silu_f(float v) {
    return v * (1.0f / (1.0f + __expf(-v)));
}

// LDS-only barrier: does NOT drain vmcnt, so global prefetch stays in flight.
__device__ __forceinline__ void bar_lds() {
    asm volatile("s_waitcnt lgkmcnt(0)\ns_barrier" ::: "memory");
}

__device__ __forceinline__ float wload(const void* p, int idx, bool f32) {
    return f32 ? ((const float*)p)[idx] : (float)((const __bf16*)p)[idx];
}

__device__ __forceinline__ bf8_t hload8(const void* p, size_t off, bool f32) {
    bf8_t v;
    if (f32) {
        const float4* q = (const float4*)((const float*)p + off);
        const float4 a = q[0], b = q[1];
        v[0]=(__bf16)a.x; v[1]=(__bf16)a.y; v[2]=(__bf16)a.z; v[3]=(__bf16)a.w;
        v[4]=(__bf16)b.x; v[5]=(__bf16)b.y; v[6]=(__bf16)b.z; v[7]=(__bf16)b.w;
    } else {
        v = *(const bf8_t*)((const __bf16*)p + off);
    }
    return v;
}

__device__ __forceinline__ int eidx(const void* ei, int i, bool i64) {
    return i64 ? (int)((const long long*)ei)[i] : ((const int*)ei)[i];
}

// ---------------------------------------------------------------------------
// dtype detection (fallback path only)
// ---------------------------------------------------------------------------
__global__ void detect_kernel(const unsigned short* __restrict__ hraw,
                              const int* __restrict__ eiraw, int* __restrict__ flags)
{
    __shared__ int s_nf, s_oddnz;
    if (threadIdx.x == 0) { s_nf = 0; s_oddnz = 0; }
    __syncthreads();
    int nf = 0;
    for (int i = threadIdx.x; i < 16384; i += blockDim.x) {
        const unsigned short u = hraw[i];
        if (((u >> 7) & 0xFF) == 0xFF) nf++;
    }
    int onz = 0;
    for (int i = threadIdx.x; i < 512; i += blockDim.x) {
        if (eiraw[2*i + 1] != 0) onz++;
    }
    if (nf)  atomicAdd(&s_nf, nf);
    if (onz) atomicAdd(&s_oddnz, onz);
    __syncthreads();
    if (threadIdx.x == 0) {
        flags[0] = (s_nf > 0) ? 1 : 0;
        flags[1] = (s_oddnz == 0) ? 1 : 0;
    }
}

// ---------------------------------------------------------------------------
// histd + inline detection: each block self-detects i64 from a 512-pair probe
// (removes the detect kernel from the critical path); block 0 additionally
// writes flags[] (f32 + i64) for all downstream kernels, which launch only
// after this kernel completes (stream order).
// ---------------------------------------------------------------------------
__global__ void histd_detect_kernel(const void* __restrict__ ei,
                                    const unsigned short* __restrict__ hraw,
                                    int* __restrict__ cnt, int* __restrict__ flags,
                                    int Ee)
{
    __shared__ int s_onz;
    __shared__ int s_nf;
    const int tid = threadIdx.x;
    if (tid == 0) { s_onz = 0; s_nf = 0; }
    __syncthreads();
    const int* ei32 = (const int*)ei;
    if (tid < 512 && ei32[2*tid + 1] != 0) s_onz = 1;   // benign multi-write
    if (blockIdx.x == 0) {
        int nf = 0;
        for (int i = tid; i < 16384; i += blockDim.x) {
            const unsigned short u = hraw[i];
            if (((u >> 7) & 0xFF) == 0xFF) nf++;
        }
        if (nf) atomicAdd(&s_nf, nf);
    }
    __syncthreads();
    const bool i64 = (s_onz == 0);
    if (blockIdx.x == 0 && tid == 0) {
        flags[0] = (s_nf > 0) ? 1 : 0;
        flags[1] = i64 ? 1 : 0;
    }
    const int e = blockIdx.x*blockDim.x + tid;
    if (e < Ee) atomicAdd(&cnt[eidx(ei, Ee + e, i64)], 1);
}

__global__ void scanA_kernel(const int* __restrict__ cnt, int* __restrict__ bsum, int Nn)
{
    __shared__ int s[512];
    const int gi = blockIdx.x*512 + threadIdx.x;
    s[threadIdx.x] = (gi < Nn) ? cnt[gi] : 0;
    __syncthreads();
    for (int off = 256; off > 0; off >>= 1) {
        if (threadIdx.x < off) s[threadIdx.x] += s[threadIdx.x + off];
        __syncthreads();
    }
    if (threadIdx.x == 0) bsum[blockIdx.x] = s[0];
}

// ---------------------------------------------------------------------------
// scanBC: fused scanB (chunk-base prefix) + scanC. Each block redundantly
// prefix-scans all nCh block sums in LDS (parallel, ~1 us) -- replaces the
// single-thread scanB kernel and one launch boundary.
// ---------------------------------------------------------------------------
__global__ void scanBC_kernel(const int* __restrict__ cnt, const int* __restrict__ bsum,
                              int* __restrict__ off, int* __restrict__ cursor,
                              int Nn, int nCh)
{
    __shared__ int sb[128];
    __shared__ int s[512];
    const int i  = threadIdx.x;
    const int b  = blockIdx.x;
    if (i < 128) sb[i] = (i < nCh) ? bsum[i] : 0;
    __syncthreads();
    for (int o = 1; o < 128; o <<= 1) {
        const int t = (i >= o && i < 128) ? sb[i - o] : 0;
        __syncthreads();
        if (i < 128) sb[i] += t;
        __syncthreads();
    }
    const int base = (b > 0) ? sb[b - 1] : 0;

    const int gi = b*512 + i;
    const int v  = (gi < Nn) ? cnt[gi] : 0;
    s[i] = v;
    __syncthreads();
    for (int o = 1; o < 512; o <<= 1) {
        const int t = (i >= o) ? s[i - o] : 0;
        __syncthreads();
        s[i] += t;
        __syncthreads();
    }
    const int excl = s[i] - v;
    if (gi <= Nn) {
        const int val = base + excl;
        off[gi] = val;
        if (gi < Nn) cursor[gi] = val;
    }
}

// ---------------------------------------------------------------------------
// Fused scatgeo + proj: blocks [0, projBlocks) run the persistent proj GEMM
// (tiles stride projBlocks); blocks [projBlocks, grid) grid-stride scatgeo,
// then zero msg/coord (stream-ordered before the edge kernel, hidden under
// the co-resident proj work).
// ---------------------------------------------------------------------------
__global__ __launch_bounds__(512, 2)
void scatgeo_proj_kernel(const void* __restrict__ ei, int* __restrict__ cursor,
                         int* __restrict__ srcs, int* __restrict__ dsts,
                         float4* __restrict__ rel4, const void* __restrict__ x,
                         const void* __restrict__ h, const void* __restrict__ We1,
                         const void* __restrict__ be1, const int* __restrict__ flags,
                         __bf16* __restrict__ PB, float* __restrict__ msg,
                         float* __restrict__ coord,
                         int Nn, int Ee, int projBlocks)
{
    __shared__ __bf16 s_h[32*136];
    const bool f32 = flags[0] != 0;
    const int tid  = threadIdx.x;

    if ((int)blockIdx.x >= projBlocks) {
        // ---------------- scatgeo path (grid-stride) ----------------
        const bool i64 = flags[1] != 0;
        const int nb = gridDim.x - projBlocks;
        const int bid = (int)blockIdx.x - projBlocks;
        for (int e = bid*512 + tid; e < Ee; e += nb*512) {
            const int s = eidx(ei, e, i64);
            const int d = eidx(ei, Ee + e, i64);
            const int p = atomicAdd(&cursor[d], 1);
            srcs[p] = s;
            dsts[p] = d;
            float r[3];
            #pragma unroll
            for (int c = 0; c < 3; ++c)
                r[c] = wload(x, s*3 + c, f32) - wload(x, d*3 + c, f32);
            float4 o; o.x = r[0]; o.y = r[1]; o.z = r[2];
            o.w = r[0]*r[0] + r[1]*r[1] + r[2]*r[2];
            rel4[p] = o;
        }
        // ---- zero msg (float4) + coord (float) ----
        {
            float4* m4 = (float4*)msg;
            const int total4 = (Nn*H) >> 2;
            const float4 z4 = {0.f, 0.f, 0.f, 0.f};
            for (int idx = bid*512 + tid; idx < total4; idx += nb*512)
                m4[idx] = z4;
            const int t3 = Nn*3;
            for (int idx = bid*512 + tid; idx < t3; idx += nb*512)
                coord[idx] = 0.f;
        }
        return;
    }

    // ---------------- proj path (persistent, stride projBlocks) ----------------
    const int wv   = tid >> 6;
    const int lane = tid & 63;
    const int quad = lane >> 4;
    const int l15  = lane & 15;

    bf8_t bW[4][2];
    float bias[2];
    #pragma unroll
    for (int t = 0; t < 2; ++t) {
        const int n    = wv*32 + t*16 + l15;
        const int rb   = (n < 128) ? 0 : 128;
        const int col  = n & 127;
        #pragma unroll
        for (int kc = 0; kc < 4; ++kc) {
            bf8_t v;
            #pragma unroll
            for (int j = 0; j < 8; ++j)
                v[j] = (__bf16)wload(We1, (rb + kc*32 + quad*8 + j)*H + col, f32);
            bW[kc][t] = v;
        }
        bias[t] = (n < 128) ? 0.f : wload(be1, col, f32);
    }

    const int tiles = (Nn + 31) >> 5;
    for (int tile = blockIdx.x; tile < tiles; tile += projBlocks) {
        const int nb2 = tile << 5;
        __syncthreads();
        {
            const int m = tid >> 4, c = tid & 15;
            int node = nb2 + m; if (node >= Nn) node = Nn - 1;
            *(bf8_t*)&s_h[m*136 + c*8] = hload8(h, (size_t)node*H + c*8, f32);
        }
        __syncthreads();

        f4_t acc[2][2];
        #pragma unroll
        for (int mm = 0; mm < 2; ++mm)
            #pragma unroll
            for (int t = 0; t < 2; ++t) acc[mm][t] = (f4_t){0.f,0.f,0.f,0.f};
        #pragma unroll
        for (int kc = 0; kc < 4; ++kc) {
            #pragma unroll
            for (int mm = 0; mm < 2; ++mm) {
                const bf8_t a = *(const bf8_t*)&s_h[(mm*16 + l15)*136 + quad*8 + kc*32];
                acc[mm][0] = MFMA16(a, bW[kc][0], acc[mm][0]);
                acc[mm][1] = MFMA16(a, bW[kc][1], acc[mm][1]);
            }
        }
        #pragma unroll
        for (int mm = 0; mm < 2; ++mm)
            #pragma unroll
            for (int i = 0; i < 4; ++i) {
                const int row = nb2 + mm*16 + quad*4 + i;
                if (row < Nn) {
                    #pragma unroll
                    for (int t = 0; t < 2; ++t)
                        PB[(size_t)row*256 + wv*32 + t*16 + l15] =
                            (__bf16)(acc[mm][t][i] + bias[t]);
                }
            }
    }
}

// ---------------------------------------------------------------------------
// Edge kernel (R11-verified, byte-identical): 64-edge dst-sorted tiles, 2
// lgkm-only barriers per tile; merge+coord for tile t-1 deferred into the
// bar1->bar2 window of tile t (double-buffered summaries).
// ---------------------------------------------------------------------------
__global__ __launch_bounds__(512, 2)
void egnn_edge_pipe_kernel(const __bf16* __restrict__ PB,
                           const int* __restrict__ srcs, const int* __restrict__ dsts,
                           const float4* __restrict__ rel4,
                           const void* __restrict__ We1,  // row 256 only (w1d)
                           const void* __restrict__ We2, const void* __restrict__ be2,
                           const void* __restrict__ Wc1, const void* __restrict__ bc1,
                           const void* __restrict__ Wc2, const int* __restrict__ flags,
                           float* __restrict__ msg, float* __restrict__ coord,
                           int Ee)
{
    const bool f32 = flags[0] != 0;
    const int tid  = threadIdx.x;
    const int wv   = tid >> 6;
    const int lane = tid & 63;
    const int quad = lane >> 4;
    const int l15  = lane & 15;
    const int mg   = wv >> 2;
    const int ng   = wv & 3;

    bf8_t bW2[4][2], bWc[4][2];
    float be2v[2], bc1v[2], wc2v[2];
    #pragma unroll
    for (int t = 0; t < 2; ++t) {
        const int n = ng*32 + t*16 + l15;
        #pragma unroll
        for (int kc = 0; kc < 4; ++kc) {
            bf8_t v, u;
            #pragma unroll
            for (int j = 0; j < 8; ++j) {
                v[j] = (__bf16)wload(We2, (kc*32 + quad*8 + j)*H + n, f32);
                u[j] = (__bf16)wload(Wc1, (kc*32 + quad*8 + j)*H + n, f32);
            }
            bW2[kc][t] = v;
            bWc[kc][t] = u;
        }
        be2v[t] = wload(be2, n, f32);
        bc1v[t] = wload(bc1, n, f32);
        wc2v[t] = wload(Wc2, n, f32);
    }

    const int em = tid >> 3;          // edge row 0..63
    const int ch = tid & 7;           // 2 column-chunks per thread
    float w1dA[8], w1dB[8];
    #pragma unroll
    for (int j = 0; j < 8; ++j) {
        w1dA[j] = wload(We1, 256*H + ch*8 + j, f32);
        w1dB[j] = wload(We1, 256*H + (ch+8)*8 + j, f32);
    }

    __shared__ __bf16 s_m1[64*136];
    __shared__ __bf16 s_m2[64*136];
    __shared__ float  s_cw[2][4*64];     // [buf][ng][edge]
    __shared__ int    s_dst[2][64];
    __shared__ float4 s_rl[2][64];
    __shared__ float  s_pre[2][8][128];  // leading-run sum per 8-row group
    __shared__ float  s_suf[2][8][128];  // trailing-run sum per 8-row group
    __shared__ int    s_wh[2][8];        // group is a single run

    const int tiles = (Ee + 63) >> 6;
    const float* rw = (const float*)rel4;

    bf8_t rA0, rA1, rB0, rB1;
    float d2cur, d2nxt;
    int   s_n, d_n, d_c;
    float4 r4c, r4n;
    {
        int e0 = blockIdx.x*64 + em; if (e0 >= Ee) e0 = Ee - 1;
        const int sc = srcs[e0], dc = dsts[e0];
        d_c = dc;
        d2cur = rw[(size_t)e0*4 + 3];
        if (ch == 0) r4c = rel4[e0];
        rA0 = *(const bf8_t*)(PB + (size_t)sc*256 + ch*8);
        rA1 = *(const bf8_t*)(PB + (size_t)sc*256 + (ch+8)*8);
        rB0 = *(const bf8_t*)(PB + (size_t)dc*256 + 128 + ch*8);
        rB1 = *(const bf8_t*)(PB + (size_t)dc*256 + 128 + (ch+8)*8);
        const int t1 = blockIdx.x + gridDim.x;
        const int tt = (t1 < tiles) ? t1 : blockIdx.x;
        int e1 = tt*64 + em; if (e1 >= Ee) e1 = Ee - 1;
        s_n = srcs[e1]; d_n = dsts[e1]; d2nxt = rw[(size_t)e1*4 + 3];
        if (ch == 0) r4n = rel4[e1];
    }

    int li = 0;
    for (int t = blockIdx.x; t < tiles; t += gridDim.x, ++li) {
        const int sb = li & 1;
        const int pb = sb ^ 1;
        // ---- stage layer-1 output + dst/rel staging ----
        {
            bf8_t o0, o1;
            #pragma unroll
            for (int j = 0; j < 8; ++j) {
                const float f0 = (float)rA0[j] + (float)rB0[j] + d2cur*w1dA[j];
                const float f1 = (float)rA1[j] + (float)rB1[j] + d2cur*w1dB[j];
                o0[j] = (__bf16)silu_f(f0);
                o1[j] = (__bf16)silu_f(f1);
            }
            *(bf8_t*)&s_m1[em*136 + ch*8]       = o0;
            *(bf8_t*)&s_m1[em*136 + (ch+8)*8]   = o1;
            if (ch == 0) { s_dst[sb][em] = d_c; s_rl[sb][em] = r4c; }
        }
        // ---- prefetch next tile ----
        {
            const int sc = s_n, dc2 = d_n;
            rA0 = *(const bf8_t*)(PB + (size_t)sc*256 + ch*8);
            rA1 = *(const bf8_t*)(PB + (size_t)sc*256 + (ch+8)*8);
            rB0 = *(const bf8_t*)(PB + (size_t)dc2*256 + 128 + ch*8);
            rB1 = *(const bf8_t*)(PB + (size_t)dc2*256 + 128 + (ch+8)*8);
            d_c = d_n; d2cur = d2nxt;
            if (ch == 0) r4c = r4n;
            const int t2 = t + 2*gridDim.x;
            const int tt = (t2 < tiles) ? t2 : t;
            int e2 = tt*64 + em; if (e2 >= Ee) e2 = Ee - 1;
            s_n = srcs[e2]; d_n = dsts[e2]; d2nxt = rw[(size_t)e2*4 + 3];
            if (ch == 0) r4n = rel4[e2];
        }
        bar_lds();

        // ---- DEFERRED: msg merge + coord scan for tile t-1 (buffers pb) ----
        if (li > 0) {
            if (tid >= 128 && tid < 256) {
                const int c = tid - 128;
                int   curd2 = __builtin_amdgcn_readfirstlane(s_dst[pb][0]);
                float cur   = 0.f;
                int   first = 1;
                #pragma unroll
                for (int gg = 0; gg < 8; ++gg) {
                    const int F  = __builtin_amdgcn_readfirstlane(s_dst[pb][gg*8]);
                    const int L  = __builtin_amdgcn_readfirstlane(s_dst[pb][gg*8 + 7]);
                    const int wh = __builtin_amdgcn_readfirstlane(s_wh[pb][gg]);
                    const float preg = s_pre[pb][gg][c];
                    const float sufg = s_suf[pb][gg][c];
                    if (F != curd2) {
                        if (first) atomicAdd(&msg[(size_t)curd2*H + c], cur);
                        else       msg[(size_t)curd2*H + c] = cur;
                        first = 0; curd2 = F; cur = 0.f;
                    }
                    if (wh) {
                        cur += sufg;
                    } else {
                        cur += preg;
                        if (first) atomicAdd(&msg[(size_t)curd2*H + c], cur);
                        else       msg[(size_t)curd2*H + c] = cur;
                        first = 0; curd2 = L; cur = sufg;
                    }
                }
                atomicAdd(&msg[(size_t)curd2*H + c], cur);  // last run: boundary
            }
            if (tid < 64) {
                const int e = tid;
                const float cwv = s_cw[pb][e] + s_cw[pb][64 + e] +
                                  s_cw[pb][128 + e] + s_cw[pb][192 + e];
                const float4 r = s_rl[pb][e];
                const int d = s_dst[pb][e];
                float vx = r.x*cwv, vy = r.y*cwv, vz = r.z*cwv;
                int   cn = 1;
                #pragma unroll
                for (int k = 1; k < 64; k <<= 1) {
                    const int   dk = __shfl_up(d,  k, 64);
                    const float xk = __shfl_up(vx, k, 64);
                    const float yk = __shfl_up(vy, k, 64);
                    const float zk = __shfl_up(vz, k, 64);
                    const int   ck = __shfl_up(cn, k, 64);
                    if (e >= k && dk == d) { vx += xk; vy += yk; vz += zk; cn += ck; }
                }
                const int dnx = __shfl_down(d, 1, 64);
                const bool runend = (e == 63) || (dnx != d);
                if (runend) {
                    const int rs = e - cn + 1;
                    if (rs == 0 || e == 63) {
                        atomicAdd(&coord[(size_t)d*3 + 0], vx);
                        atomicAdd(&coord[(size_t)d*3 + 1], vy);
                        atomicAdd(&coord[(size_t)d*3 + 2], vz);
                    } else {
                        coord[(size_t)d*3 + 0] = vx;
                        coord[(size_t)d*3 + 1] = vy;
                        coord[(size_t)d*3 + 2] = vz;
                    }
                }
            }
        }

        // ---- layer 2: m2 = silu(m1 @ We2 + be2) ----
        {
            f4_t a2[2][2];
            #pragma unroll
            for (int mm = 0; mm < 2; ++mm)
                #pragma unroll
                for (int h2 = 0; h2 < 2; ++h2) a2[mm][h2] = (f4_t){0.f,0.f,0.f,0.f};
            #pragma unroll
            for (int kc = 0; kc < 4; ++kc) {
                #pragma unroll
                for (int mm = 0; mm < 2; ++mm) {
                    const bf8_t a = *(const bf8_t*)&s_m1[(mg*32 + mm*16 + l15)*136 + quad*8 + kc*32];
                    a2[mm][0] = MFMA16(a, bW2[kc][0], a2[mm][0]);
                    a2[mm][1] = MFMA16(a, bW2[kc][1], a2[mm][1]);
                }
            }
            #pragma unroll
            for (int mm = 0; mm < 2; ++mm)
                #pragma unroll
                for (int i = 0; i < 4; ++i) {
                    const int m = mg*32 + mm*16 + quad*4 + i;
                    s_m2[m*136 + ng*32 + l15]      = (__bf16)silu_f(a2[mm][0][i] + be2v[0]);
                    s_m2[m*136 + ng*32 + 16 + l15] = (__bf16)silu_f(a2[mm][1][i] + be2v[1]);
                }
        }
        bar_lds();

        // ---- layer 3: coord head partials -> s_cw[sb] ----
        {
            f4_t a3[2][2];
            #pragma unroll
            for (int mm = 0; mm < 2; ++mm)
                #pragma unroll
                for (int h2 = 0; h2 < 2; ++h2) a3[mm][h2] = (f4_t){0.f,0.f,0.f,0.f};
            #pragma unroll
            for (int kc = 0; kc < 4; ++kc) {
                #pragma unroll
                for (int mm = 0; mm < 2; ++mm) {
                    const bf8_t a = *(const bf8_t*)&s_m2[(mg*32 + mm*16 + l15)*136 + quad*8 + kc*32];
                    a3[mm][0] = MFMA16(a, bWc[kc][0], a3[mm][0]);
                    a3[mm][1] = MFMA16(a, bWc[kc][1], a3[mm][1]);
                }
            }
            float p[2][4];
            #pragma unroll
            for (int mm = 0; mm < 2; ++mm)
                #pragma unroll
                for (int i = 0; i < 4; ++i) {
                    const float v0 = silu_f(a3[mm][0][i] + bc1v[0]);
                    const float v1 = silu_f(a3[mm][1][i] + bc1v[1]);
                    p[mm][i] = v0*wc2v[0] + v1*wc2v[1];
                }
            #pragma unroll
            for (int off = 1; off < 16; off <<= 1)
                #pragma unroll
                for (int mm = 0; mm < 2; ++mm)
                    #pragma unroll
                    for (int i = 0; i < 4; ++i) p[mm][i] += __shfl_xor(p[mm][i], off, 64);
            if (l15 == 0) {
                #pragma unroll
                for (int mm = 0; mm < 2; ++mm)
                    #pragma unroll
                    for (int i = 0; i < 4; ++i)
                        s_cw[sb][ng*64 + (mg*32 + mm*16 + quad*4 + i)] = p[mm][i];
            }
        }

        // ---- msg per-group scan -> s_pre/s_suf/s_wh[sb] + interior stores ----
        {
            const int rbase = wv << 3;
            const int c0    = lane << 1;
            int   curd = __builtin_amdgcn_readfirstlane(s_dst[sb][rbase]);
            float ax = 0.f, ay = 0.f;
            float px = 0.f, py = 0.f;
            int   predone = 0;
            #pragma unroll
            for (int i = 0; i < 8; ++i) {
                const int d = __builtin_amdgcn_readfirstlane(s_dst[sb][rbase + i]);
                const bf2_t v = *(const bf2_t*)&s_m2[(rbase + i)*136 + c0];
                const float vx = (float)v[0], vy = (float)v[1];
                if (d != curd) {
                    if (!predone) { px = ax; py = ay; predone = 1; }
                    else {
                        float2 st; st.x = ax; st.y = ay;
                        *(float2*)&msg[(size_t)curd*H + c0] = st;   // interior run
                    }
                    curd = d; ax = vx; ay = vy;
                } else { ax += vx; ay += vy; }
            }
            s_pre[sb][wv][c0]   = px;  s_pre[sb][wv][c0+1] = py;
            s_suf[sb][wv][c0]   = ax;  s_suf[sb][wv][c0+1] = ay;
            if (lane == 0) s_wh[sb][wv] = !predone;
        }
        // no 3rd barrier: merge+coord for this tile run after next bar1
    }

    // ---- epilogue: flush merge + coord for the final tile ----
    if (li > 0) {
        bar_lds();
        const int pb = (li - 1) & 1;
        if (tid >= 128 && tid < 256) {
            const int c = tid - 128;
            int   curd2 = __builtin_amdgcn_readfirstlane(s_dst[pb][0]);
            float cur   = 0.f;
            int   first = 1;
            #pragma unroll
            for (int gg = 0; gg < 8; ++gg) {
                const int F  = __builtin_amdgcn_readfirstlane(s_dst[pb][gg*8]);
                const int L  = __builtin_amdgcn_readfirstlane(s_dst[pb][gg*8 + 7]);
                const int wh = __builtin_amdgcn_readfirstlane(s_wh[pb][gg]);
                const float preg = s_pre[pb][gg][c];
                const float sufg = s_suf[pb][gg][c];
                if (F != curd2) {
                    if (first) atomicAdd(&msg[(size_t)curd2*H + c], cur);
                    else       msg[(size_t)curd2*H + c] = cur;
                    first = 0; curd2 = F; cur = 0.f;
                }
                if (wh) {
                    cur += sufg;
                } else {
                    cur += preg;
                    if (first) atomicAdd(&msg[(size_t)curd2*H + c], cur);
                    else       msg[(size_t)curd2*H + c] = cur;
                    first = 0; curd2 = L; cur = sufg;
                }
            }
            atomicAdd(&msg[(size_t)curd2*H + c], cur);
        }
        if (tid < 64) {
            const int e = tid;
            const float cwv = s_cw[pb][e] + s_cw[pb][64 + e] +
                              s_cw[pb][128 + e] + s_cw[pb][192 + e];
            const float4 r = s_rl[pb][e];
            const int d = s_dst[pb][e];
            float vx = r.x*cwv, vy = r.y*cwv, vz = r.z*cwv;
            int   cn = 1;
            #pragma unroll
            for (int k = 1; k < 64; k <<= 1) {
                const int   dk = __shfl_up(d,  k, 64);
                const float xk = __shfl_up(vx, k, 64);
                const float yk = __shfl_up(vy, k, 64);
                const float zk = __shfl_up(vz, k, 64);
                const int   ck = __shfl_up(cn, k, 64);
                if (e >= k && dk == d) { vx += xk; vy += yk; vz += zk; cn += ck; }
            }
            const int dnx = __shfl_down(d, 1, 64);
            const bool runend = (e == 63) || (dnx != d);
            if (runend) {
                const int rs = e - cn + 1;
                if (rs == 0 || e == 63) {
                    atomicAdd(&coord[(size_t)d*3 + 0], vx);
                    atomicAdd(&coord[(size_t)d*3 + 1], vy);
                    atomicAdd(&coord[(size_t)d*3 + 2], vz);
                } else {
                    coord[(size_t)d*3 + 0] = vx;
                    coord[(size_t)d*3 + 1] = vy;
                    coord[(size_t)d*3 + 2] = vz;
                }
            }
        }
    }
}

// ---------------------------------------------------------------------------
// Node kernel: h_out = h + silu([h | msg] @ Wn1 + bn1) @ Wn2 + bn2
// msg is f32. Optionally also emits x_out = x + coord (do_x).
// ---------------------------------------------------------------------------
__global__ __launch_bounds__(512, 2)
void egnn_node_kernel(const void* __restrict__ h, const float* __restrict__ msg,
                      const void* __restrict__ Wn1, const void* __restrict__ bn1,
                      const void* __restrict__ Wn2, const void* __restrict__ bn2,
                      const int* __restrict__ flags, void* __restrict__ h_out,
                      const void* __restrict__ x, const float* __restrict__ coord,
                      size_t obase, int do_x, int Nn)
{
    const bool f32 = flags[0] != 0;
    const int tid  = threadIdx.x;
    const int wv   = tid >> 6;
    const int lane = tid & 63;
    const int quad = lane >> 4;
    const int l15  = lane & 15;
    const int mg   = wv >> 2;
    const int ng   = wv & 3;

    bf8_t bW1[8][2];
    bf8_t bW2[4][2];
    float b1v[2], b2v[2];
    #pragma unroll
    for (int t = 0; t < 2; ++t) {
        const int n = ng*32 + t*16 + l15;
        #pragma unroll
        for (int kc = 0; kc < 8; ++kc) {
            bf8_t v;
            #pragma unroll
            for (int j = 0; j < 8; ++j) v[j] = (__bf16)wload(Wn1, (kc*32 + quad*8 + j)*H + n, f32);
            bW1[kc][t] = v;
        }
        #pragma unroll
        for (int kc = 0; kc < 4; ++kc) {
            bf8_t v;
            #pragma unroll
            for (int j = 0; j < 8; ++j) v[j] = (__bf16)wload(Wn2, (kc*32 + quad*8 + j)*H + n, f32);
            bW2[kc][t] = v;
        }
        b1v[t] = wload(bn1, n, f32);
        b2v[t] = wload(bn2, n, f32);
    }

    __shared__ __bf16 s_in[32*264];
    __shared__ __bf16 s_t1[32*136];

    const int tiles = (Nn + 31) >> 5;
    for (int tile = blockIdx.x; tile < tiles; tile += gridDim.x) {
        const int nb = tile << 5;
        __syncthreads();
        #pragma unroll
        for (int r = 0; r < 2; ++r) {
            const int idx = tid + r*512;
            const int m = idx >> 5, c = idx & 31;
            int node = nb + m;
            if (node >= Nn) node = Nn - 1;
            if (c < 16) {
                *(bf8_t*)&s_in[m*264 + c*8] = hload8(h, (size_t)node*H + c*8, f32);
            } else {
                const float4* mp = (const float4*)(msg + (size_t)node*H + (c - 16)*8);
                const float4 v0 = mp[0], v1 = mp[1];
                __bf16* d = &s_in[m*264 + c*8];
                d[0] = (__bf16)v0.x; d[1] = (__bf16)v0.y; d[2] = (__bf16)v0.z; d[3] = (__bf16)v0.w;
                d[4] = (__bf16)v1.x; d[5] = (__bf16)v1.y; d[6] = (__bf16)v1.z; d[7] = (__bf16)v1.w;
            }
        }
        // x_out epilogue (independent of LDS)
        if (do_x && tid < 96) {
            const int m = tid / 3, c = tid - m*3;
            const int node = nb + m;
            if (node < Nn) {
                const float xv = wload(x, node*3 + c, f32);
                const float o = xv + coord[(size_t)node*3 + c];
                if (f32) ((float*)h_out)[obase + (size_t)node*3 + c] = o;
                else     ((__bf16*)h_out)[obase + (size_t)node*3 + c] = (__bf16)o;
            }
        }
        __syncthreads();

        {
            f4_t a0 = {0.f,0.f,0.f,0.f}, a1 = {0.f,0.f,0.f,0.f};
            const int abase = (mg*16 + l15)*264 + quad*8;
            #pragma unroll
            for (int kc = 0; kc < 8; ++kc) {
                const bf8_t a = *(const bf8_t*)&s_in[abase + kc*32];
                a0 = MFMA16(a, bW1[kc][0], a0);
                a1 = MFMA16(a, bW1[kc][1], a1);
            }
            #pragma unroll
            for (int i = 0; i < 4; ++i) {
                const int m = mg*16 + quad*4 + i;
                s_t1[m*136 + ng*32 + l15]      = (__bf16)silu_f(a0[i] + b1v[0]);
                s_t1[m*136 + ng*32 + 16 + l15] = (__bf16)silu_f(a1[i] + b1v[1]);
            }
        }
        __syncthreads();

        {
            f4_t a0 = {0.f,0.f,0.f,0.f}, a1 = {0.f,0.f,0.f,0.f};
            const int abase = (mg*16 + l15)*136 + quad*8;
            #pragma unroll
            for (int kc = 0; kc < 4; ++kc) {
                const bf8_t a = *(const bf8_t*)&s_t1[abase + kc*32];
                a0 = MFMA16(a, bW2[kc][0], a0);
                a1 = MFMA16(a, bW2[kc][1], a1);
            }
            #pragma unroll
            for (int i = 0; i < 4; ++i) {
                const int node = nb + mg*16 + quad*4 + i;
                if (node < Nn) {
                    const int n0 = ng*32 + l15, n1 = n0 + 16;
                    const size_t i0 = (size_t)node*H + n0, i1 = (size_t)node*H + n1;
                    const float h0 = f32 ? ((const float*)h)[i0] : (float)((const __bf16*)h)[i0];
                    const float h1 = f32 ? ((const float*)h)[i1] : (float)((const __bf16*)h)[i1];
                    const float o0 = a0[i] + b2v[0] + h0;
                    const float o1 = a1[i] + b2v[1] + h1;
                    if (f32) {
                        ((float*)h_out)[i0] = o0;
                        ((float*)h_out)[i1] = o1;
                    } else {
                        ((__bf16*)h_out)[i0] = (__bf16)o0;
                        ((__bf16*)h_out)[i1] = (__bf16)o1;
                    }
                }
            }
        }
    }
}

// ---------------------------------------------------------------------------
// Fallback (R2 atomic path)
// ---------------------------------------------------------------------------
__global__ void cvt_ei_kernel(const void* __restrict__ src, int* __restrict__ dst,
                              int n, const int* __restrict__ flags)
{
    const int i = blockIdx.x*blockDim.x + threadIdx.x;
    if (i >= n) return;
    dst[i] = flags[1] ? (int)((const long long*)src)[i] : ((const int*)src)[i];
}

__global__ __launch_bounds__(512, 2)
void egnn_edge_kernel(const void* __restrict__ h, const void* __restrict__ x,
                      const int* __restrict__ ei,
                      const void* __restrict__ We1, const void* __restrict__ be1,
                      const void* __restrict__ We2, const void* __restrict__ be2,
                      const void* __restrict__ Wc1, const void* __restrict__ bc1,
                      const void* __restrict__ Wc2, const int* __restrict__ flags,
                      float* __restrict__ msg_agg, float* __restrict__ coord_agg,
                      int Nn, int Ee)
{
    const bool f32 = flags[0] != 0;
    const int tid  = threadIdx.x;
    const int wv   = tid >> 6;
    const int lane = tid & 63;
    const int quad = lane >> 4;
    const int l15  = lane & 15;
    const int mg   = wv >> 2;
    const int ng   = wv & 3;

    bf8_t bW1[8][2];
    bf8_t bW2[4][2];
    bf8_t bWc[4][2];
    float be1v[2], be2v[2], bc1v[2], w1dv[2], wc2v[2];
    #pragma unroll
    for (int t = 0; t < 2; ++t) {
        const int n = ng*32 + t*16 + l15;
        #pragma unroll
        for (int kc = 0; kc < 8; ++kc) {
            bf8_t v;
            #pragma unroll
            for (int j = 0; j < 8; ++j) v[j] = (__bf16)wload(We1, (kc*32 + quad*8 + j)*H + n, f32);
            bW1[kc][t] = v;
        }
        #pragma unroll
        for (int kc = 0; kc < 4; ++kc) {
            bf8_t v, u;
            #pragma unroll
            for (int j = 0; j < 8; ++j) {
                v[j] = (__bf16)wload(We2, (kc*32 + quad*8 + j)*H + n, f32);
                u[j] = (__bf16)wload(Wc1, (kc*32 + quad*8 + j)*H + n, f32);
            }
            bW2[kc][t] = v;
            bWc[kc][t] = u;
        }
        be1v[t] = wload(be1, n, f32);
        be2v[t] = wload(be2, n, f32);
        bc1v[t] = wload(bc1, n, f32);
        w1dv[t] = wload(We1, 256*H + n, f32);
        wc2v[t] = wload(Wc2, n, f32);
    }

    __shared__ __bf16 s_in[32*264];
    __shared__ __bf16 s_m1[32*136];
    __shared__ __bf16 s_m2[32*136];
    __shared__ float  s_rel[32*3];
    __shared__ float  s_dist[32];
    __shared__ int    s_dstv[32];
    __shared__ float  s_cw[32*4];

    const int tiles = Ee >> 5;
    for (int tile = blockIdx.x; tile < tiles; tile += gridDim.x) {
        const int ebase = tile << 5;
        __syncthreads();

        if (tid < 32) {
            const int e  = ebase + tid;
            const int sn = ei[e];
            const int dn = ei[Ee + e];
            s_dstv[tid] = dn;
            float d2 = 0.f;
            #pragma unroll
            for (int c = 0; c < 3; ++c) {
                float r;
                if (f32) r = ((const float*)x)[sn*3 + c] - ((const float*)x)[dn*3 + c];
                else     r = (float)((const __bf16*)x)[sn*3 + c] - (float)((const __bf16*)x)[dn*3 + c];
                s_rel[tid*3 + c] = r;
                d2 += r*r;
            }
            s_dist[tid] = d2;
        }
        #pragma unroll
        for (int r = 0; r < 2; ++r) {
            const int idx = tid + r*512;
            const int m = idx >> 5, c = idx & 31;
            const int e = ebase + m;
            const int node = (c < 16) ? ei[e] : ei[Ee + e];
            *(bf8_t*)&s_in[m*264 + c*8] = hload8(h, (size_t)node*H + (c & 15)*8, f32);
        }
        __syncthreads();

        {
            f4_t a0 = {0.f,0.f,0.f,0.f}, a1 = {0.f,0.f,0.f,0.f};
            const int abase = (mg*16 + l15)*264 + quad*8;
            #pragma unroll
            for (int kc = 0; kc < 8; ++kc) {
                const bf8_t a = *(const bf8_t*)&s_in[abase + kc*32];
                a0 = MFMA16(a, bW1[kc][0], a0);
                a1 = MFMA16(a, bW1[kc][1], a1);
            }
            #pragma unroll
            for (int i = 0; i < 4; ++i) {
                const int m = mg*16 + quad*4 + i;
                const float d2 = s_dist[m];
                s_m1[m*136 + ng*32 + l15]      = (__bf16)silu_f(a0[i] + d2*w1dv[0] + be1v[0]);
                s_m1[m*136 + ng*32 + 16 + l15] = (__bf16)silu_f(a1[i] + d2*w1dv[1] + be1v[1]);
            }
        }
        __syncthreads();

        {
            f4_t a0 = {0.f,0.f,0.f,0.f}, a1 = {0.f,0.f,0.f,0.f};
            const int abase = (mg*16 + l15)*136 + quad*8;
            #pragma unroll
            for (int kc = 0; kc < 4; ++kc) {
                const bf8_t a = *(const bf8_t*)&s_m1[abase + kc*32];
                a0 = MFMA16(a, bW2[kc][0], a0);
                a1 = MFMA16(a, bW2[kc][1], a1);
            }
            #pragma unroll
            for (int i = 0; i < 4; ++i) {
                const int m = mg*16 + quad*4 + i;
                const float v0 = silu_f(a0[i] + be2v[0]);
                const float v1 = silu_f(a1[i] + be2v[1]);
                s_m2[m*136 + ng*32 + l15]      = (__bf16)v0;
                s_m2[m*136 + ng*32 + 16 + l15] = (__bf16)v1;
                const size_t db = (size_t)s_dstv[m]*H + ng*32 + l15;
                atomicAdd(&msg_agg[db],      v0);
                atomicAdd(&msg_agg[db + 16], v1);
            }
        }
        __syncthreads();

        {
            f4_t a0 = {0.f,0.f,0.f,0.f}, a1 = {0.f,0.f,0.f,0.f};
            const int abase = (mg*16 + l15)*136 + quad*8;
            #pragma unroll
            for (int kc = 0; kc < 4; ++kc) {
                const bf8_t a = *(const bf8_t*)&s_m2[abase + kc*32];
                a0 = MFMA16(a, bWc[kc][0], a0);
                a1 = MFMA16(a, bWc[kc][1], a1);
            }
            float p[4];
            #pragma unroll
            for (int i = 0; i < 4; ++i) {
                const float v0 = silu_f(a0[i] + bc1v[0]);
                const float v1 = silu_f(a1[i] + bc1v[1]);
                p[i] = v0*wc2v[0] + v1*wc2v[1];
            }
            #pragma unroll
            for (int off = 1; off < 16; off <<= 1) {
                #pragma unroll
                for (int i = 0; i < 4; ++i) p[i] += __shfl_xor(p[i], off, 64);
            }
            if (l15 == 0) {
                #pragma unroll
                for (int i = 0; i < 4; ++i)
                    s_cw[(mg*16 + quad*4 + i)*4 + ng] = p[i];
            }
        }
        __syncthreads();

        if (tid < 96) {
            const int m = tid / 3, c = tid - m*3;
            const float cw = s_cw[m*4 + 0] + s_cw[m*4 + 1] + s_cw[m*4 + 2] + s_cw[m*4 + 3];
            atomicAdd(&coord_agg[(size_t)s_dstv[m]*3 + c], s_rel[m*3 + c]*cw);
        }
    }
}

__global__ void egnn_x_kernel(const void* __restrict__ x, const float* __restrict__ coord_agg,
                              const int* __restrict__ flags, void* __restrict__ out,
                              size_t obase, int total)
{
    const bool f32 = flags[0] != 0;
    const int i = blockIdx.x*blockDim.x + threadIdx.x;
    if (i >= total) return;
    const float xv = f32 ? ((const float*)x)[i] : (float)((const __bf16*)x)[i];
    const float o = xv + coord_agg[i];
    if (f32) ((float*)out)[obase + i] = o;
    else     ((__bf16*)out)[obase + i] = (__bf16)o;
}

static inline size_t align256(size_t v) { return (v + 255) & ~(size_t)255; }

extern "C" void kernel_launch(void* const* d_in, const int* in_sizes, int n_in,
                              void* d_out, int out_size, void* d_ws, size_t ws_size,
                              hipStream_t stream)
{
    const void* h   = d_in[0];
    const void* x   = d_in[1];
    const void* ei0 = d_in[2];
    const void* We1 = d_in[3];
    const void* be1 = d_in[4];
    const void* We2 = d_in[5];
    const void* be2 = d_in[6];
    const void* Wc1 = d_in[7];
    const void* bc1 = d_in[8];
    const void* Wc2 = d_in[9];
    const void* Wn1 = d_in[10];
    const void* bn1 = d_in[11];
    const void* Wn2 = d_in[12];
    const void* bn2 = d_in[13];

    const int Nn = in_sizes[0] / H;   // 50000
    const int Ee = in_sizes[2] / 2;   // 640000

    char* ws = (char*)d_ws;
    size_t o = 0;
    size_t o_cnt   = o; o = align256(o + (size_t)Nn*4);        // zeroed (memset)
    size_t o_msg   = o; o = align256(o + (size_t)Nn*H*4);      // zeroed in scatgeo
    size_t o_coord = o; o = align256(o + (size_t)Nn*3*4);      // zeroed in scatgeo
    size_t o_srcs  = o; o = align256(o + (size_t)Ee*4);
    size_t o_dsts  = o; o = align256(o + (size_t)Ee*4);
    size_t o_rel   = o; o = align256(o + (size_t)Ee*16);       // rel4 (xyz, d2)
    size_t o_pb    = o; o = align256(o + (size_t)Nn*256*2);    // PB bf16 [N,256]
    size_t o_off   = o; o = align256(o + (size_t)(Nn+1)*4);
    size_t o_cur   = o; o = align256(o + (size_t)Nn*4);
    size_t o_bsum  = o; o = align256(o + 512*4);
    size_t o_base  = o; o = align256(o + 512*4);
    size_t o_flags = o; o = align256(o + 64);
    const size_t need_csr = o;

    const int nCh = (Nn + 1 + 511) / 512;

    if (ws_size >= need_csr) {
        int*    cnt     = (int*)   (ws + o_cnt);
        float*  msg     = (float*) (ws + o_msg);
        float*  coord   = (float*) (ws + o_coord);
        int*    srcs    = (int*)   (ws + o_srcs);
        int*    dsts    = (int*)   (ws + o_dsts);
        float4* rel4    = (float4*)(ws + o_rel);
        __bf16* PB      = (__bf16*)(ws + o_pb);
        int*    off     = (int*)   (ws + o_off);
        int*    cursor  = (int*)   (ws + o_cur);
        int*    bsum    = (int*)   (ws + o_bsum);
        int*    flags   = (int*)   (ws + o_flags);

        hipMemsetAsync(cnt, 0, (size_t)Nn*4, stream);
        histd_detect_kernel<<<(Ee + 511)/512, 512, 0, stream>>>(ei0,
                                                 (const unsigned short*)h, cnt, flags, Ee);
        scanA_kernel<<<nCh, 512, 0, stream>>>(cnt, bsum, Nn);
        scanBC_kernel<<<nCh, 512, 0, stream>>>(cnt, bsum, off, cursor, Nn, nCh);

        // fused: 256 persistent proj blocks + 256 grid-stride scatgeo blocks
        // (which also zero msg/coord), all co-resident.
        scatgeo_proj_kernel<<<512, 512, 0, stream>>>(ei0, cursor, srcs, dsts, rel4,
                                                     x, h, We1, be1, flags, PB,
                                                     msg, coord, Nn, Ee, 256);

        // grid 512: ~20 tiles/block, 2 blocks/CU (R5-proven best config)
        egnn_edge_pipe_kernel<<<512, 512, 0, stream>>>(PB, srcs, dsts, rel4,
                                                       We1, We2, be2, Wc1, bc1, Wc2,
                                                       flags, msg, coord, Ee);

        egnn_node_kernel<<<1024, 512, 0, stream>>>(h, msg, Wn1, bn1, Wn2, bn2,
                                                   flags, d_out, x, coord,
                                                   (size_t)Nn*H, 1, Nn);
    } else {
        // fallback: proven R2 atomic path
        float* msg_agg   = (float*)ws;
        float* coord_agg = (float*)(ws + (size_t)Nn*H*4);
        int*   ei        = (int*)  (ws + (size_t)Nn*H*4 + (size_t)Nn*3*4);
        int*   flags     = (int*)  (ws + (size_t)Nn*H*4 + (size_t)Nn*3*4 + (size_t)2*Ee*4);

        detect_kernel<<<1, 256, 0, stream>>>((const unsigned short*)h, (const int*)ei0, flags);
        cvt_ei_kernel<<<(2*Ee + 255)/256, 256, 0, stream>>>(ei0, ei, 2*Ee, flags);
        hipMemsetAsync(msg_agg,   0, (size_t)Nn*H*4, stream);
        hipMemsetAsync(coord_agg, 0, (size_t)Nn*3*4, stream);
        egnn_edge_kernel<<<1024, 512, 0, stream>>>(h, x, ei, We1, be1, We2, be2,
                                                   Wc1, bc1, Wc2, flags,
                                                   msg_agg, coord_agg, Nn, Ee);
        egnn_node_kernel<<<512, 512, 0, stream>>>(h, msg_agg, Wn1, bn1, Wn2, bn2,
                                                  flags, d_out, x, coord_agg,
                                                  (size_t)Nn*H, 0, Nn);
        egnn_x_kernel<<<(Nn*3 + 255)/256, 256, 0, stream>>>(x, coord_agg, flags, d_out,
                                                            (size_t)Nn*H, Nn*3);
    }
}